// Round 1
// baseline (1970.128 us; speedup 1.0000x reference)
//
#include <hip/hip_runtime.h>

#define A_SCALE_C 0.6454972243679028f   // (24/10)^-0.5
#define E_SCALE_C 0.3952847075210474f   // (64/10)^-0.5

static __device__ __forceinline__ float waveSum(float v){
#pragma unroll
  for (int off = 32; off; off >>= 1) v += __shfl_xor(v, off, 64);
  return v;
}

static __device__ __forceinline__ float silu(float g){
  return g / (1.0f + __expf(-g));
}

// ---------------- utility kernels ----------------

// out[c][d] = w[c][d] * nw[c]   (256x128), grid 128 x 256
__global__ void scale_wout_kernel(const float* __restrict__ w, const float* __restrict__ nw,
                                  float* __restrict__ out){
  int idx = blockIdx.x*256 + threadIdx.x;
  out[idx] = w[idx] * nw[idx >> 7];
}

__global__ void copy4_kernel(const float4* __restrict__ src, float4* __restrict__ dst, int n4){
  int idx = blockIdx.x*256 + threadIdx.x;
  if (idx < n4) dst[idx] = src[idx];
}

// rows of 128: one wave per row, block 256 = 4 rows
__global__ void rmsnorm128_kernel(const float* __restrict__ x, const float* __restrict__ w,
                                  float* __restrict__ out, int nrows){
  int row = blockIdx.x*4 + (threadIdx.x >> 6);
  int lane = threadIdx.x & 63;
  if (row >= nrows) return;
  const float* xr = x + (size_t)row*128;
  float2 v = *(const float2*)(xr + lane*2);
  float ss = waveSum(v.x*v.x + v.y*v.y);
  float rs = rsqrtf(ss*(1.0f/128.0f) + 1e-6f);
  float2 wv = *(const float2*)(w + lane*2);
  float2 o; o.x = v.x*rs*wv.x; o.y = v.y*rs*wv.y;
  *(float2*)(out + (size_t)row*128 + lane*2) = o;
}

// env[e][d] = sum_k rbf[e][k]*w[k][d]   grid 4096 x 256 (8192*128 outputs)
__global__ __launch_bounds__(256) void env_kernel(const float* __restrict__ rbf,
                                                  const float* __restrict__ w,
                                                  float* __restrict__ env){
  __shared__ float wL[12*128];
  int t = threadIdx.x;
  for (int idx=t; idx<12*128; idx+=256) wL[idx] = w[idx];
  __syncthreads();
  int base = blockIdx.x*256 + t;
  int e = base >> 7, d = base & 127;
  float acc = 0.f;
#pragma unroll
  for (int k=0;k<12;k++) acc = fmaf(rbf[e*12+k], wL[k*128+d], acc);
  env[base] = acc;
}

// node_out[n] += partial[2n] + partial[2n+1]   grid 128 x 128
__global__ void node_add_partials_kernel(const float* __restrict__ partial,
                                         float* __restrict__ node_out){
  int n = blockIdx.x, t = threadIdx.x;
  node_out[n*128 + t] += partial[(2*n)*128 + t] + partial[(2*n+1)*128 + t];
}

// node_out[n] += E_SCALE * (partial[2n]+partial[2n+1]) @ nproj   grid 128 x 128
__global__ void node_final_kernel(const float* __restrict__ partial,
                                  const float* __restrict__ nproj,
                                  float* __restrict__ node_out){
  __shared__ float seg[128];
  int n = blockIdx.x, t = threadIdx.x;
  seg[t] = partial[(2*n)*128 + t] + partial[(2*n+1)*128 + t];
  __syncthreads();
  float acc = 0.f;
  for (int dd=0; dd<128; dd++) acc = fmaf(seg[dd], nproj[dd*128 + t], acc);
  node_out[n*128 + t] += acc * E_SCALE_C;
}

// block-2 gate + per-dim softmax over each node's 64 edges.  grid 128 x 256
__global__ __launch_bounds__(256) void blk2_scores_kernel(const float* __restrict__ e_n,
                                                          const float* __restrict__ gate_w,
                                                          float* __restrict__ scores){
  __shared__ float lds[64*128];
  const int t = threadIdx.x, n = blockIdx.x;
  for (int idx=t; idx<64*128; idx+=256) lds[idx] = e_n[(size_t)n*64*128 + idx];
  __syncthreads();
  const int d = t & 127, rg = (t >> 7) * 32;
  float ga[32];
#pragma unroll
  for (int i=0;i<32;i++) ga[i] = 0.f;
  for (int k=0;k<128;k+=4){
    float g0 = gate_w[(k+0)*128 + d];
    float g1 = gate_w[(k+1)*128 + d];
    float g2 = gate_w[(k+2)*128 + d];
    float g3 = gate_w[(k+3)*128 + d];
#pragma unroll
    for (int i=0;i<32;i++){
      const float4 f = *(const float4*)&lds[(rg+i)*128 + k];
      ga[i] = fmaf(f.x,g0,ga[i]); ga[i] = fmaf(f.y,g1,ga[i]);
      ga[i] = fmaf(f.z,g2,ga[i]); ga[i] = fmaf(f.w,g3,ga[i]);
    }
  }
  __syncthreads();
#pragma unroll
  for (int i=0;i<32;i++) lds[(rg+i)*128 + d] = ga[i] * E_SCALE_C;
  __syncthreads();
  if (t < 128){
    float m = -1e30f;
    for (int r=0;r<64;r++) m = fmaxf(m, lds[r*128 + t]);
    float S = 0.f;
    for (int r=0;r<64;r++) S += __expf(lds[r*128 + t] - m);
    float inv = 1.f/(S + 1e-12f);
    for (int r=0;r<64;r++)
      scores[(size_t)(n*64 + r)*128 + t] = __expf(lds[r*128 + t] - m) * inv;
  }
}

// ---------------- fused angle-segment kernel (blocks 1 and 3) ----------------
// one workgroup = one eij segment = 24 angle rows.  grid 3072 x 256
template<bool IS_BLK1>
__global__ __launch_bounds__(256) void angle_block_kernel(
    const float* __restrict__ angle,     // [73728][64] raw
    const float* __restrict__ node,      // [128][128] current node state
    const float* __restrict__ e_n,       // [8192][128] normalized edge
    const float* __restrict__ norm_a,    // [64]
    const float* __restrict__ win,       // [448][512]
    const float* __restrict__ wout_s,    // [256][128] nw-folded
    const float* __restrict__ gate_w,    // blk1: [448][128]
    const float* __restrict__ env,       // blk3: [8192][128]
    const float* __restrict__ a_sw,      // blk3: [73728]
    const float* __restrict__ aproj,     // blk3: [128][64]
    const float* __restrict__ eproj,     // blk3: [128][128]
    float* __restrict__ edge_out,        // [8192][128] (+=)
    float* __restrict__ angle_out)       // blk3: [73728][64]
{
  __shared__ float lds[12440];
  const int t = threadIdx.x;
  const int s = blockIdx.x;
  const int loc = s / 24;
  const int j = s % 24;
  const int eij = loc*64 + j;
  float* feat = lds;                       // [24][448]

  // ---- stage feat ----
  {
    const float* arow = angle + (size_t)s*24*64;
    for (int idx=t; idx<24*64; idx+=256)
      feat[(idx>>6)*448 + (idx&63)] = arow[idx];
    for (int idx=t; idx<24*128; idx+=256){
      int r = idx>>7, c = idx&127;
      feat[r*448 + 64 + c] = node[loc*128 + c];
    }
    for (int idx=t; idx<24*128; idx+=256){
      int r = idx>>7, c = idx&127;
      feat[r*448 + 192 + c] = e_n[(size_t)eij*128 + c];
    }
    for (int idx=t; idx<24*128; idx+=256){
      int r = idx>>7, c = idx&127;
      feat[r*448 + 320 + c] = e_n[(size_t)(loc*64 + r)*128 + c];
    }
  }
  __syncthreads();
  // inline rmsnorm of the angle part (64 dims)
  {
    const int wv = t >> 6, lane = t & 63;
    for (int r=wv; r<24; r+=4){
      float x = feat[r*448 + lane];
      float ss = waveSum(x*x);
      float rs = rsqrtf(ss*(1.0f/64.0f) + 1e-6f);
      feat[r*448 + lane] = x*rs*norm_a[lane];
    }
  }
  __syncthreads();

  // ---- hidden GEMM: thread t owns v-col t and g-col t+256 for all 24 rows ----
  float vacc[24], gacc[24];
#pragma unroll
  for (int r=0;r<24;r++){ vacc[r]=0.f; gacc[r]=0.f; }
  for (int k=0;k<448;k+=4){
    float w0v = win[(k+0)*512 + t];
    float w1v = win[(k+1)*512 + t];
    float w2v = win[(k+2)*512 + t];
    float w3v = win[(k+3)*512 + t];
    float w0g = win[(k+0)*512 + 256 + t];
    float w1g = win[(k+1)*512 + 256 + t];
    float w2g = win[(k+2)*512 + 256 + t];
    float w3g = win[(k+3)*512 + 256 + t];
#pragma unroll
    for (int r=0;r<24;r++){
      const float4 f = *(const float4*)&feat[r*448 + k];
      vacc[r] = fmaf(f.x,w0v,vacc[r]); vacc[r] = fmaf(f.y,w1v,vacc[r]);
      vacc[r] = fmaf(f.z,w2v,vacc[r]); vacc[r] = fmaf(f.w,w3v,vacc[r]);
      gacc[r] = fmaf(f.x,w0g,gacc[r]); gacc[r] = fmaf(f.y,w1g,gacc[r]);
      gacc[r] = fmaf(f.z,w2g,gacc[r]); gacc[r] = fmaf(f.w,w3g,gacc[r]);
    }
  }

  const int d  = t & 127;
  const int rg = (t >> 7) * 12;
  float ga[12];
  if constexpr (IS_BLK1){
#pragma unroll
    for (int i=0;i<12;i++) ga[i]=0.f;
    for (int k=0;k<448;k+=4){
      float g0 = gate_w[(k+0)*128 + d];
      float g1 = gate_w[(k+1)*128 + d];
      float g2 = gate_w[(k+2)*128 + d];
      float g3 = gate_w[(k+3)*128 + d];
#pragma unroll
      for (int i=0;i<12;i++){
        const float4 f = *(const float4*)&feat[(rg+i)*448 + k];
        ga[i] = fmaf(f.x,g0,ga[i]); ga[i] = fmaf(f.y,g1,ga[i]);
        ga[i] = fmaf(f.z,g2,ga[i]); ga[i] = fmaf(f.w,g3,ga[i]);
      }
    }
  }
  __syncthreads();   // feat dead; overlay
  float* vg    = lds;            // [24][256]
  float* gateL = lds + 6144;     // [24][128]
  float* msgL  = lds + 9216;     // [24][128]
  float* rsL   = lds + 12288;    // [24]
  float* segL  = lds + 12312;    // [128]

#pragma unroll
  for (int r=0;r<24;r++) vg[r*256 + t] = vacc[r] * silu(gacc[r]);
  if constexpr (IS_BLK1){
#pragma unroll
    for (int i=0;i<12;i++) gateL[(rg+i)*128 + d] = ga[i] * A_SCALE_C;
  }
  __syncthreads();
  // per-row rms over 256
  {
    const int wv = t >> 6, lane = t & 63;
    for (int r=wv; r<24; r+=4){
      const float4 v = *(const float4*)&vg[r*256 + lane*4];
      float ss = waveSum(v.x*v.x + v.y*v.y + v.z*v.z + v.w*v.w);
      if (lane == 0) rsL[r] = rsqrtf(ss*(1.0f/256.0f) + 1e-6f);
    }
  }
  __syncthreads();
  // ---- out GEMM: 12 rows per thread-half, K=256 ----
  float macc[12];
#pragma unroll
  for (int i=0;i<12;i++) macc[i]=0.f;
  for (int c=0;c<256;c+=4){
    float w0 = wout_s[(c+0)*128 + d];
    float w1 = wout_s[(c+1)*128 + d];
    float w2 = wout_s[(c+2)*128 + d];
    float w3 = wout_s[(c+3)*128 + d];
#pragma unroll
    for (int i=0;i<12;i++){
      const float4 v = *(const float4*)&vg[(rg+i)*256 + c];
      macc[i] = fmaf(v.x,w0,macc[i]); macc[i] = fmaf(v.y,w1,macc[i]);
      macc[i] = fmaf(v.z,w2,macc[i]); macc[i] = fmaf(v.w,w3,macc[i]);
    }
  }
#pragma unroll
  for (int i=0;i<12;i++) msgL[(rg+i)*128 + d] = macc[i] * rsL[rg+i];
  __syncthreads();

  if constexpr (IS_BLK1){
    // per-dim softmax over the 24 rows, then weighted reduce into edge
    if (t < 128){
      float ex[24]; float m = -1e30f;
#pragma unroll
      for (int r=0;r<24;r++){ ex[r] = gateL[r*128 + t]; m = fmaxf(m, ex[r]); }
      float S = 0.f;
#pragma unroll
      for (int r=0;r<24;r++){ ex[r] = __expf(ex[r] - m); S += ex[r]; }
      float inv = 1.f/(S + 1e-12f);
      float delta = 0.f;
#pragma unroll
      for (int r=0;r<24;r++) delta += msgL[r*128 + t] * ex[r];
      edge_out[(size_t)eij*128 + t] += delta * inv;
    }
  } else {
    // angle update: angle += a_sw * (msg @ aproj)
    {
      const int c = t & 63, ra = (t >> 6) * 6;
      float aacc[6];
#pragma unroll
      for (int i=0;i<6;i++) aacc[i]=0.f;
      for (int dd=0; dd<128; dd++){
        float w = aproj[dd*64 + c];
#pragma unroll
        for (int i=0;i<6;i++) aacc[i] = fmaf(msgL[(ra+i)*128 + dd], w, aacc[i]);
      }
#pragma unroll
      for (int i=0;i<6;i++){
        size_t a = (size_t)s*24 + ra + i;
        angle_out[a*64 + c] = angle[a*64 + c] + aacc[i] * a_sw[a];
      }
    }
    // edge update: edge += A_SCALE * (sum_r msg*env[eik]*a_sw) @ eproj
    if (t < 128){
      float seg = 0.f;
#pragma unroll
      for (int r=0;r<24;r++){
        float aw = a_sw[(size_t)s*24 + r];
        seg += msgL[r*128 + t] * env[(size_t)(loc*64 + r)*128 + t] * aw;
      }
      segL[t] = seg;
    }
    __syncthreads();
    if (t < 128){
      float acc = 0.f;
      for (int dd=0; dd<128; dd++) acc = fmaf(segL[dd], eproj[dd*128 + t], acc);
      edge_out[(size_t)eij*128 + t] += acc * A_SCALE_C;
    }
  }
}

// ---------------- fused edge-group kernel (blocks 2 and 4) ----------------
// one workgroup = 32 edges (half of one node's segment).  grid 256 x 256
// MODE 0: aa (node attention partials), 1: ae (edge MLP), 2: ar (refine)
template<int MODE>
__global__ __launch_bounds__(256) void edge_block_kernel(
    const float* __restrict__ e_n,       // [8192][128]
    const float* __restrict__ n_n,       // [128][128]
    const int*   __restrict__ next2e,    // [8192]
    const float* __restrict__ win,       // [384][512]
    const float* __restrict__ wout_s,    // [256][128]
    const float* __restrict__ scores,    // MODE0
    const float* __restrict__ env,       // MODE2
    const float* __restrict__ sw,        // MODE2
    const float* __restrict__ eproj,     // MODE2 [128][128]
    float* __restrict__ edge_out,        // MODE1,2 (+=)
    float* __restrict__ partial)         // MODE0,2 [256][128]
{
  __shared__ float lds[12320];
  const int t = threadIdx.x;
  const int g = blockIdx.x;
  const int e0 = g*32;
  const int n = e0 >> 6;
  float* feat = lds;                     // [32][384]

  for (int idx=t; idx<32*128; idx+=256){
    int r = idx>>7, c = idx&127;
    feat[r*384 + c] = e_n[(size_t)(e0+r)*128 + c];
  }
  for (int idx=t; idx<32*128; idx+=256){
    int r = idx>>7, c = idx&127;
    feat[r*384 + 128 + c] = n_n[n*128 + c];
  }
  for (int idx=t; idx<32*128; idx+=256){
    int r = idx>>7, c = idx&127;
    int nx = next2e[e0 + r];
    feat[r*384 + 256 + c] = n_n[nx*128 + c];
  }
  __syncthreads();

  float vacc[32], gacc[32];
#pragma unroll
  for (int r=0;r<32;r++){ vacc[r]=0.f; gacc[r]=0.f; }
  for (int k=0;k<384;k+=4){
    float w0v = win[(k+0)*512 + t];
    float w1v = win[(k+1)*512 + t];
    float w2v = win[(k+2)*512 + t];
    float w3v = win[(k+3)*512 + t];
    float w0g = win[(k+0)*512 + 256 + t];
    float w1g = win[(k+1)*512 + 256 + t];
    float w2g = win[(k+2)*512 + 256 + t];
    float w3g = win[(k+3)*512 + 256 + t];
#pragma unroll
    for (int r=0;r<32;r++){
      const float4 f = *(const float4*)&feat[r*384 + k];
      vacc[r] = fmaf(f.x,w0v,vacc[r]); vacc[r] = fmaf(f.y,w1v,vacc[r]);
      vacc[r] = fmaf(f.z,w2v,vacc[r]); vacc[r] = fmaf(f.w,w3v,vacc[r]);
      gacc[r] = fmaf(f.x,w0g,gacc[r]); gacc[r] = fmaf(f.y,w1g,gacc[r]);
      gacc[r] = fmaf(f.z,w2g,gacc[r]); gacc[r] = fmaf(f.w,w3g,gacc[r]);
    }
  }
  __syncthreads();  // feat dead
  float* vg   = lds;             // [32][256]
  float* msgL = lds + 8192;      // [32][128]
  float* rsL  = lds + 12288;     // [32]

#pragma unroll
  for (int r=0;r<32;r++) vg[r*256 + t] = vacc[r] * silu(gacc[r]);
  __syncthreads();
  {
    const int wv = t >> 6, lane = t & 63;
    for (int r=wv; r<32; r+=4){
      const float4 v = *(const float4*)&vg[r*256 + lane*4];
      float ss = waveSum(v.x*v.x + v.y*v.y + v.z*v.z + v.w*v.w);
      if (lane == 0) rsL[r] = rsqrtf(ss*(1.0f/256.0f) + 1e-6f);
    }
  }
  __syncthreads();
  const int d  = t & 127;
  const int rg = (t >> 7) * 16;
  float macc[16];
#pragma unroll
  for (int i=0;i<16;i++) macc[i]=0.f;
  for (int c=0;c<256;c+=4){
    float w0 = wout_s[(c+0)*128 + d];
    float w1 = wout_s[(c+1)*128 + d];
    float w2 = wout_s[(c+2)*128 + d];
    float w3 = wout_s[(c+3)*128 + d];
#pragma unroll
    for (int i=0;i<16;i++){
      const float4 v = *(const float4*)&vg[(rg+i)*256 + c];
      macc[i] = fmaf(v.x,w0,macc[i]); macc[i] = fmaf(v.y,w1,macc[i]);
      macc[i] = fmaf(v.z,w2,macc[i]); macc[i] = fmaf(v.w,w3,macc[i]);
    }
  }
#pragma unroll
  for (int i=0;i<16;i++) msgL[(rg+i)*128 + d] = macc[i] * rsL[rg+i];
  __syncthreads();

  if constexpr (MODE == 0){
    if (t < 128){
      float p = 0.f;
#pragma unroll
      for (int r=0;r<32;r++) p += msgL[r*128 + t] * scores[(size_t)(e0+r)*128 + t];
      partial[g*128 + t] = p;
    }
  } else if constexpr (MODE == 1){
#pragma unroll
    for (int i=0;i<16;i++)
      edge_out[(size_t)(e0+rg+i)*128 + d] += msgL[(rg+i)*128 + d];
  } else {
    float eacc[16];
#pragma unroll
    for (int i=0;i<16;i++) eacc[i]=0.f;
    for (int dd=0; dd<128; dd++){
      float w = eproj[dd*128 + d];
#pragma unroll
      for (int i=0;i<16;i++) eacc[i] = fmaf(msgL[(rg+i)*128 + dd], w, eacc[i]);
    }
#pragma unroll
    for (int i=0;i<16;i++)
      edge_out[(size_t)(e0+rg+i)*128 + d] += eacc[i];
    if (t < 128){
      float p = 0.f;
#pragma unroll
      for (int r=0;r<32;r++)
        p += msgL[r*128 + t] * env[(size_t)(e0+r)*128 + t] * sw[e0 + r];
      partial[g*128 + t] = p;
    }
  }
}

// ---------------- launch ----------------
extern "C" void kernel_launch(void* const* d_in, const int* in_sizes, int n_in,
                              void* d_out, int out_size, void* d_ws, size_t ws_size,
                              hipStream_t stream){
  const float* node_in  = (const float*)d_in[0];
  const float* edge_in  = (const float*)d_in[1];
  const float* angle_in = (const float*)d_in[2];
  const float* sw       = (const float*)d_in[3];
  const float* a_sw     = (const float*)d_in[4];
  const float* rbf      = (const float*)d_in[5];
  const int*   edge_index = (const int*)d_in[6];
  const float* la_norm_e = (const float*)d_in[8];
  const float* la_norm_a = (const float*)d_in[9];
  const float* la_win    = (const float*)d_in[10];
  const float* la_nw     = (const float*)d_in[11];
  const float* la_wout   = (const float*)d_in[12];
  const float* la_gate   = (const float*)d_in[13];
  const float* aa_norm_n = (const float*)d_in[14];
  const float* aa_norm_e = (const float*)d_in[15];
  const float* aa_win    = (const float*)d_in[16];
  const float* aa_nw     = (const float*)d_in[17];
  const float* aa_wout   = (const float*)d_in[18];
  const float* aa_src_gate = (const float*)d_in[19];
  const float* ae_win    = (const float*)d_in[20];
  const float* ae_nw     = (const float*)d_in[21];
  const float* ae_wout   = (const float*)d_in[22];
  const float* lr_norm_e = (const float*)d_in[23];
  const float* lr_norm_a = (const float*)d_in[24];
  const float* lr_win    = (const float*)d_in[25];
  const float* lr_nw     = (const float*)d_in[26];
  const float* lr_wout   = (const float*)d_in[27];
  const float* lr_env    = (const float*)d_in[28];
  const float* lr_eproj  = (const float*)d_in[29];
  const float* lr_aproj  = (const float*)d_in[30];
  const float* ar_norm_n = (const float*)d_in[31];
  const float* ar_norm_e = (const float*)d_in[32];
  const float* ar_win    = (const float*)d_in[33];
  const float* ar_nw     = (const float*)d_in[34];
  const float* ar_wout   = (const float*)d_in[35];
  const float* ar_env    = (const float*)d_in[36];
  const float* ar_nproj  = (const float*)d_in[37];
  const float* ar_eproj  = (const float*)d_in[38];

  float* out_node  = (float*)d_out;                     // [128][128]
  float* out_edge  = out_node + 128*128;                // [8192][128]
  float* out_angle = out_edge + (size_t)8192*128;       // [73728][64]

  float* p = (float*)d_ws;
  float* e_n = p;      p += (size_t)8192*128;
  float* n_n = p;      p += 128*128;
  float* scores2 = p;  p += (size_t)8192*128;
  float* env = p;      p += (size_t)8192*128;
  float* partial = p;  p += 256*128;
  float* ws_la = p;    p += 256*128;
  float* ws_aa = p;    p += 256*128;
  float* ws_ae = p;    p += 256*128;
  float* ws_lr = p;    p += 256*128;
  float* ws_ar = p;    p += 256*128;

  dim3 b256(256), b128(128);
  const int* next2e = edge_index + 8192;

  // prep: fold gmlp rmsnorm weight into w_out; init output buffers
  scale_wout_kernel<<<128, b256, 0, stream>>>(la_wout, la_nw, ws_la);
  scale_wout_kernel<<<128, b256, 0, stream>>>(aa_wout, aa_nw, ws_aa);
  scale_wout_kernel<<<128, b256, 0, stream>>>(ae_wout, ae_nw, ws_ae);
  scale_wout_kernel<<<128, b256, 0, stream>>>(lr_wout, lr_nw, ws_lr);
  scale_wout_kernel<<<128, b256, 0, stream>>>(ar_wout, ar_nw, ws_ar);
  copy4_kernel<<<1024, b256, 0, stream>>>((const float4*)edge_in, (float4*)out_edge, 262144);
  copy4_kernel<<<16,   b256, 0, stream>>>((const float4*)node_in, (float4*)out_node, 4096);

  // ---- block 1: line-graph attention (angle -> edge) ----
  rmsnorm128_kernel<<<2048, b256, 0, stream>>>(edge_in, la_norm_e, e_n, 8192);
  angle_block_kernel<true><<<3072, b256, 0, stream>>>(angle_in, node_in, e_n, la_norm_a,
      la_win, ws_la, la_gate, nullptr, nullptr, nullptr, nullptr, out_edge, nullptr);

  // ---- block 2: atom-graph attention (edge -> node) + edge MLP ----
  rmsnorm128_kernel<<<2048, b256, 0, stream>>>(out_edge, aa_norm_e, e_n, 8192);
  rmsnorm128_kernel<<<32,   b256, 0, stream>>>(node_in, aa_norm_n, n_n, 128);
  blk2_scores_kernel<<<128, b256, 0, stream>>>(e_n, aa_src_gate, scores2);
  edge_block_kernel<0><<<256, b256, 0, stream>>>(e_n, n_n, next2e, aa_win, ws_aa,
      scores2, nullptr, nullptr, nullptr, nullptr, partial);
  edge_block_kernel<1><<<256, b256, 0, stream>>>(e_n, n_n, next2e, ae_win, ws_ae,
      nullptr, nullptr, nullptr, nullptr, out_edge, nullptr);
  node_add_partials_kernel<<<128, b128, 0, stream>>>(partial, out_node);

  // ---- block 3: line-graph refinement ----
  rmsnorm128_kernel<<<2048, b256, 0, stream>>>(out_edge, lr_norm_e, e_n, 8192);
  env_kernel<<<4096, b256, 0, stream>>>(rbf, lr_env, env);
  angle_block_kernel<false><<<3072, b256, 0, stream>>>(angle_in, out_node, e_n, lr_norm_a,
      lr_win, ws_lr, nullptr, env, a_sw, lr_aproj, lr_eproj, out_edge, out_angle);

  // ---- block 4: atom-graph refinement ----
  rmsnorm128_kernel<<<2048, b256, 0, stream>>>(out_edge, ar_norm_e, e_n, 8192);
  rmsnorm128_kernel<<<32,   b256, 0, stream>>>(out_node, ar_norm_n, n_n, 128);
  env_kernel<<<4096, b256, 0, stream>>>(rbf, ar_env, env);
  edge_block_kernel<2><<<256, b256, 0, stream>>>(e_n, n_n, next2e, ar_win, ws_ar,
      nullptr, env, sw, ar_eproj, out_edge, partial);
  node_final_kernel<<<128, b128, 0, stream>>>(partial, ar_nproj, out_node);

  (void)in_sizes; (void)n_in; (void)out_size; (void)ws_size;
}

// Round 2
// 807.144 us; speedup vs baseline: 2.4409x; 2.4409x over previous
//
#include <hip/hip_runtime.h>

#define A_SCALE_C 0.6454972243679028f   // (24/10)^-0.5
#define E_SCALE_C 0.3952847075210474f   // (64/10)^-0.5

typedef unsigned short u16;
typedef unsigned int u32;
typedef __attribute__((ext_vector_type(8))) short bf16x8;
typedef __attribute__((ext_vector_type(4))) float f32x4;

static __device__ __forceinline__ float waveSum(float v){
#pragma unroll
  for (int off = 32; off; off >>= 1) v += __shfl_xor(v, off, 64);
  return v;
}
static __device__ __forceinline__ float silu(float g){
  return g / (1.0f + __expf(-g));
}
static __device__ __forceinline__ float bf2f(u16 h){
  union { u32 u; float f; } x; x.u = ((u32)h) << 16; return x.f;
}
static __device__ __forceinline__ u16 f2bf(float f){
  union { float f; u32 u; } x; x.f = f;
  u32 r = x.u + 0x7FFFu + ((x.u >> 16) & 1u);
  return (u16)(r >> 16);
}

// ---------------- small prep kernels ----------------

// wout_s[c][d] = w[c][d]*nw[c]  (256x128 fp32)
__global__ void scale_wout_kernel(const float* __restrict__ w, const float* __restrict__ nw,
                                  float* __restrict__ out){
  int idx = blockIdx.x*256 + threadIdx.x;
  out[idx] = w[idx] * nw[idx >> 7];
}

__global__ void copy4_kernel(const float4* __restrict__ src, float4* __restrict__ dst, int n4){
  int idx = blockIdx.x*256 + threadIdx.x;
  if (idx < n4) dst[idx] = src[idx];
}

// dst[(c0+c)*K + k] = bf16(src[(row0+k)*src_ld + c] * scale[k])  (transposed bf16 weights)
__global__ void build_wt_kernel(const float* __restrict__ src, int src_ld, int row0,
                                const float* __restrict__ rowscale,
                                u16* __restrict__ dst, int c0, int total, int klog){
  int idx = blockIdx.x*256 + threadIdx.x;
  if (idx >= total) return;
  int K = 1 << klog;
  int c = idx >> klog, k = idx & (K-1);
  float s = rowscale ? rowscale[k] : 1.0f;
  dst[(size_t)(c0+c)*K + k] = f2bf(src[(size_t)(row0+k)*src_ld + c] * s);
}

// angle_hat bf16 (rmsnorm over 64 dims, no weight)
__global__ void rmsnorm64_hat_kernel(const float* __restrict__ ang, u16* __restrict__ hat){
  int row = blockIdx.x*4 + (threadIdx.x >> 6);
  int lane = threadIdx.x & 63;
  float x = ang[(size_t)row*64 + lane];
  float ss = waveSum(x*x);
  float rs = rsqrtf(ss*(1.0f/64.0f) + 1e-6f);
  hat[(size_t)row*64 + lane] = f2bf(x*rs);
}

// full rmsnorm rows of 128 -> bf16
__global__ void rmsnorm128_bf16_kernel(const float* __restrict__ x, const float* __restrict__ w,
                                       u16* __restrict__ out, int nrows){
  int row = blockIdx.x*4 + (threadIdx.x >> 6);
  int lane = threadIdx.x & 63;
  if (row >= nrows) return;
  float2 v = *(const float2*)(x + (size_t)row*128 + lane*2);
  float ss = waveSum(v.x*v.x + v.y*v.y);
  float rs = rsqrtf(ss*(1.0f/128.0f) + 1e-6f);
  float2 wv = *(const float2*)(w + lane*2);
  u32 pk = (u32)f2bf(v.x*rs*wv.x) | ((u32)f2bf(v.y*rs*wv.y) << 16);
  *(u32*)(out + (size_t)row*128 + lane*2) = pk;
}

// compact rmsnorm: 3072 used-edge rows (loc*64+j, j<24) -> bf16
__global__ void rmsnorm128c_bf16_kernel(const float* __restrict__ x, const float* __restrict__ w,
                                        u16* __restrict__ out){
  int row = blockIdx.x*4 + (threadIdx.x >> 6);   // 0..3071
  int lane = threadIdx.x & 63;
  int src = (row/24)*64 + row%24;
  float2 v = *(const float2*)(x + (size_t)src*128 + lane*2);
  float ss = waveSum(v.x*v.x + v.y*v.y);
  float rs = rsqrtf(ss*(1.0f/128.0f) + 1e-6f);
  float2 wv = *(const float2*)(w + lane*2);
  u32 pk = (u32)f2bf(v.x*rs*wv.x) | ((u32)f2bf(v.y*rs*wv.y) << 16);
  *(u32*)(out + (size_t)row*128 + lane*2) = pk;
}

// fp32 rmsnorm rows of 128 (node tables)
__global__ void rmsnorm128_kernel(const float* __restrict__ x, const float* __restrict__ w,
                                  float* __restrict__ out, int nrows){
  int row = blockIdx.x*4 + (threadIdx.x >> 6);
  int lane = threadIdx.x & 63;
  if (row >= nrows) return;
  float2 v = *(const float2*)(x + (size_t)row*128 + lane*2);
  float ss = waveSum(v.x*v.x + v.y*v.y);
  float rs = rsqrtf(ss*(1.0f/128.0f) + 1e-6f);
  float2 wv = *(const float2*)(w + lane*2);
  float2 o; o.x = v.x*rs*wv.x; o.y = v.y*rs*wv.y;
  *(float2*)(out + (size_t)row*128 + lane*2) = o;
}

// env[e][d] = sum_k rbf[e][k]*w[k][d]
__global__ __launch_bounds__(256) void env_kernel(const float* __restrict__ rbf,
                                                  const float* __restrict__ w,
                                                  float* __restrict__ env){
  __shared__ float wL[12*128];
  int t = threadIdx.x;
  for (int idx=t; idx<12*128; idx+=256) wL[idx] = w[idx];
  __syncthreads();
  int base = blockIdx.x*256 + t;
  int e = base >> 7, d = base & 127;
  float acc = 0.f;
#pragma unroll
  for (int k=0;k<12;k++) acc = fmaf(rbf[e*12+k], wL[k*128+d], acc);
  env[base] = acc;
}

// node tables: C[row][c_off+col] = sum_k A[row][k] * B[(b_row0+k)*b_ld + col]
__global__ __launch_bounds__(128) void node_gemm_kernel(const float* __restrict__ A,
    const float* __restrict__ B, int b_ld, int b_row0,
    float* __restrict__ C, int c_ld, int c_off){
  __shared__ float ar[128];
  int row = blockIdx.x, t = threadIdx.x;
  ar[t] = A[row*128 + t];
  __syncthreads();
  int col = blockIdx.y*128 + t;
  float acc = 0.f;
  for (int k=0;k<128;k++) acc = fmaf(ar[k], B[(size_t)(b_row0+k)*b_ld + col], acc);
  C[(size_t)row*c_ld + c_off + col] = acc;
}

// ---------------- MFMA GEMM: C[M][N]bf16 = A[M][K]bf16 @ Bt[N][K]^T ----------------
// grid (M/32, N/128), block 256 (4 waves); K in {64,128}
__global__ __launch_bounds__(256) void gemm_bf16_kernel(
    const u16* __restrict__ A, const u16* __restrict__ Bt, u16* __restrict__ C,
    int N, int K){
  __shared__ float cl[32*128];
  const int lane = threadIdx.x & 63, wave = threadIdx.x >> 6;
  const size_t arow = (size_t)blockIdx.x*32;
  const size_t bcol = (size_t)blockIdx.y*128 + wave*32;
  f32x4 acc00={0,0,0,0}, acc01={0,0,0,0}, acc10={0,0,0,0}, acc11={0,0,0,0};
  for (int k=0; k<K; k+=32){
    int ko = k + (lane>>4)*8;
    bf16x8 a0 = *(const bf16x8*)(A + (arow + (lane&15))*K + ko);
    bf16x8 a1 = *(const bf16x8*)(A + (arow + 16 + (lane&15))*K + ko);
    bf16x8 b0 = *(const bf16x8*)(Bt + (bcol + (lane&15))*K + ko);
    bf16x8 b1 = *(const bf16x8*)(Bt + (bcol + 16 + (lane&15))*K + ko);
    acc00 = __builtin_amdgcn_mfma_f32_16x16x32_bf16(a0, b0, acc00, 0,0,0);
    acc01 = __builtin_amdgcn_mfma_f32_16x16x32_bf16(a0, b1, acc01, 0,0,0);
    acc10 = __builtin_amdgcn_mfma_f32_16x16x32_bf16(a1, b0, acc10, 0,0,0);
    acc11 = __builtin_amdgcn_mfma_f32_16x16x32_bf16(a1, b1, acc11, 0,0,0);
  }
  const int cr = (lane>>4)*4, cc = wave*32 + (lane&15);
#pragma unroll
  for (int q=0;q<4;q++){
    cl[(cr+q)*128 + cc]      = acc00[q];
    cl[(cr+q)*128 + cc+16]   = acc01[q];
    cl[(16+cr+q)*128 + cc]    = acc10[q];
    cl[(16+cr+q)*128 + cc+16] = acc11[q];
  }
  __syncthreads();
  const int t = threadIdx.x;
  size_t base = arow*N + (size_t)blockIdx.y*128;
#pragma unroll
  for (int i=0;i<16;i++){
    int idx = i*256 + t; int r = idx>>7, c = idx&127;
    C[base + (size_t)r*N + c] = f2bf(cl[idx]);
  }
}

// ---------------- fused angle kernel (blocks 1 and 3) ----------------
// one workgroup = one eij segment (24 angle rows). grid 768 per chunk of 32 locs.
template<bool IS_BLK1>
__global__ __launch_bounds__(256) void angle_fused_kernel(
    const float* __restrict__ angle, const u16* __restrict__ P,
    const u16* __restrict__ preE, const float* __restrict__ NP,
    const float* __restrict__ wout, const float* __restrict__ env,
    const float* __restrict__ a_sw, const float* __restrict__ aproj,
    const float* __restrict__ eproj, float* __restrict__ edge_out,
    float* __restrict__ angle_out, int loc0){
  constexpr int PW  = IS_BLK1 ? 640 : 512;
  constexpr int EW  = IS_BLK1 ? 1280 : 1024;
  constexpr int NPW = IS_BLK1 ? 640 : 512;
  __shared__ float vg[24*256];
  __shared__ float msgL[24*128];
  __shared__ float auxL[24*128];   // blk1: gate; blk3: unused (seg uses segL)
  __shared__ float rsL[24];
  __shared__ float segL[128];
  const int t = threadIdx.x;
  const int sl = blockIdx.x;
  const int locl = sl / 24, j = sl % 24;
  const int loc = loc0 + locl;
  const int sg = loc*24 + j;           // compact eij row
  const int eij = loc*64 + j;

  // hidden = P(angle part) + preE(eij) + preE(eik) + NP(node)
  float base_v = NP[loc*NPW + t]       + bf2f(preE[(size_t)sg*EW + t]);
  float base_g = NP[loc*NPW + 256 + t] + bf2f(preE[(size_t)sg*EW + 256 + t]);
  const size_t prow = ((size_t)locl*576 + (size_t)j*24) * PW;
  for (int r=0; r<24; r++){
    const size_t ik = (size_t)(loc*24 + r)*EW + 512;
    float v = bf2f(P[prow + (size_t)r*PW + t])       + bf2f(preE[ik + t])       + base_v;
    float g = bf2f(P[prow + (size_t)r*PW + 256 + t]) + bf2f(preE[ik + 256 + t]) + base_g;
    vg[r*256 + t] = v * silu(g);
  }
  __syncthreads();
  // per-row rms over 256
  {
    const int wv = t >> 6, lane = t & 63;
    for (int r=wv; r<24; r+=4){
      const float4 v = *(const float4*)&vg[r*256 + lane*4];
      float ss = waveSum(v.x*v.x + v.y*v.y + v.z*v.z + v.w*v.w);
      if (lane == 0) rsL[r] = rsqrtf(ss*(1.0f/256.0f) + 1e-6f);
    }
  }
  const int d  = t & 127;
  const int rg = (t >> 7) * 12;
  if constexpr (IS_BLK1){
    // gate values from decomposed parts
    float gbase = NP[loc*640 + 512 + d] + bf2f(preE[(size_t)sg*1280 + 1024 + d]);
#pragma unroll
    for (int i=0;i<12;i++){
      float gv = bf2f(P[prow + (size_t)(rg+i)*640 + 512 + d])
               + bf2f(preE[(size_t)(loc*24 + rg+i)*1280 + 1152 + d]) + gbase;
      auxL[(rg+i)*128 + d] = gv * A_SCALE_C;
    }
  }
  __syncthreads();
  // out-GEMM: 12 rows per half, K=256
  float macc[12];
#pragma unroll
  for (int i=0;i<12;i++) macc[i]=0.f;
  for (int c=0;c<256;c+=4){
    float w0 = wout[(c+0)*128 + d];
    float w1 = wout[(c+1)*128 + d];
    float w2 = wout[(c+2)*128 + d];
    float w3 = wout[(c+3)*128 + d];
#pragma unroll
    for (int i=0;i<12;i++){
      const float4 v = *(const float4*)&vg[(rg+i)*256 + c];
      macc[i] = fmaf(v.x,w0,macc[i]); macc[i] = fmaf(v.y,w1,macc[i]);
      macc[i] = fmaf(v.z,w2,macc[i]); macc[i] = fmaf(v.w,w3,macc[i]);
    }
  }
#pragma unroll
  for (int i=0;i<12;i++) msgL[(rg+i)*128 + d] = macc[i] * rsL[rg+i];
  __syncthreads();

  if constexpr (IS_BLK1){
    if (t < 128){
      float ex[24]; float m = -1e30f;
#pragma unroll
      for (int r=0;r<24;r++){ ex[r] = auxL[r*128 + t]; m = fmaxf(m, ex[r]); }
      float S = 0.f;
#pragma unroll
      for (int r=0;r<24;r++){ ex[r] = __expf(ex[r] - m); S += ex[r]; }
      float inv = 1.f/(S + 1e-12f);
      float delta = 0.f;
#pragma unroll
      for (int r=0;r<24;r++) delta += msgL[r*128 + t] * ex[r];
      edge_out[(size_t)eij*128 + t] += delta * inv;
    }
  } else {
    // angle update: angle += a_sw * (msg @ aproj)
    {
      const int c = t & 63, ra = (t >> 6) * 6;
      float aacc[6];
#pragma unroll
      for (int i=0;i<6;i++) aacc[i]=0.f;
      for (int dd=0; dd<128; dd++){
        float w = aproj[dd*64 + c];
#pragma unroll
        for (int i=0;i<6;i++) aacc[i] = fmaf(msgL[(ra+i)*128 + dd], w, aacc[i]);
      }
      const size_t a0 = (size_t)(loc*24 + j)*24;
#pragma unroll
      for (int i=0;i<6;i++){
        size_t a = a0 + ra + i;
        angle_out[a*64 + c] = angle[a*64 + c] + aacc[i] * a_sw[a];
      }
    }
    if (t < 128){
      const size_t a0 = (size_t)(loc*24 + j)*24;
      float seg = 0.f;
#pragma unroll
      for (int r=0;r<24;r++){
        float aw = a_sw[a0 + r];
        seg += msgL[r*128 + t] * env[(size_t)(loc*64 + r)*128 + t] * aw;
      }
      segL[t] = seg;
    }
    __syncthreads();
    if (t < 128){
      float acc = 0.f;
      for (int dd=0; dd<128; dd++) acc = fmaf(segL[dd], eproj[dd*128 + t], acc);
      edge_out[(size_t)eij*128 + t] += acc * A_SCALE_C;
    }
  }
}

// blk2 per-dim softmax over each node's 64 edges; gate comes from He cols 1024..1151
__global__ __launch_bounds__(256) void scores_kernel(const u16* __restrict__ He,
                                                     float* __restrict__ scores){
  __shared__ float s[64*128];
  const int t = threadIdx.x, n = blockIdx.x;
  for (int idx=t; idx<64*128; idx+=256){
    int r = idx>>7, c = idx&127;
    s[idx] = bf2f(He[(size_t)(n*64+r)*1152 + 1024 + c]) * E_SCALE_C;
  }
  __syncthreads();
  if (t < 128){
    float m = -1e30f;
    for (int r=0;r<64;r++) m = fmaxf(m, s[r*128 + t]);
    float S = 0.f;
    for (int r=0;r<64;r++) S += __expf(s[r*128 + t] - m);
    float inv = 1.f/(S + 1e-12f);
    for (int r=0;r<64;r++)
      scores[(size_t)(n*64 + r)*128 + t] = __expf(s[r*128 + t] - m) * inv;
  }
}

// ---------------- fused edge kernel (blocks 2 and 4) ----------------
// one workgroup = 16 edges. grid 512. MODE 0: aa partials, 1: ae edge+=, 2: ar refine
template<int MODE>
__global__ __launch_bounds__(256) void edge_fused_kernel(
    const u16* __restrict__ He, int he_ld, int he_off,
    const float* __restrict__ NPt,      // [128][1024] self(512)|nbr(512)
    const int* __restrict__ next2e,
    const float* __restrict__ wout,
    const float* __restrict__ scores, const float* __restrict__ env,
    const float* __restrict__ sw, const float* __restrict__ eproj,
    float* __restrict__ edge_out, float* __restrict__ partial){
  __shared__ float vg[16*256];
  __shared__ float msgL[16*128];
  __shared__ float rsL[16];
  __shared__ int nxL[16];
  const int t = threadIdx.x, g = blockIdx.x, e0 = g*16, n = e0 >> 6;
  if (t < 16) nxL[t] = next2e[e0 + t];
  __syncthreads();
  float bv = NPt[n*1024 + t], bg = NPt[n*1024 + 256 + t];
  for (int r=0;r<16;r++){
    int nx = nxL[r];
    float v  = bf2f(He[(size_t)(e0+r)*he_ld + he_off + t])       + bv + NPt[nx*1024 + 512 + t];
    float gg = bf2f(He[(size_t)(e0+r)*he_ld + he_off + 256 + t]) + bg + NPt[nx*1024 + 768 + t];
    vg[r*256 + t] = v * silu(gg);
  }
  __syncthreads();
  {
    const int wv = t >> 6, lane = t & 63;
    for (int r=wv; r<16; r+=4){
      const float4 v = *(const float4*)&vg[r*256 + lane*4];
      float ss = waveSum(v.x*v.x + v.y*v.y + v.z*v.z + v.w*v.w);
      if (lane == 0) rsL[r] = rsqrtf(ss*(1.0f/256.0f) + 1e-6f);
    }
  }
  __syncthreads();
  const int d  = t & 127;
  const int rg = (t >> 7) * 8;
  float macc[8];
#pragma unroll
  for (int i=0;i<8;i++) macc[i]=0.f;
  for (int c=0;c<256;c+=4){
    float w0 = wout[(c+0)*128 + d];
    float w1 = wout[(c+1)*128 + d];
    float w2 = wout[(c+2)*128 + d];
    float w3 = wout[(c+3)*128 + d];
#pragma unroll
    for (int i=0;i<8;i++){
      const float4 v = *(const float4*)&vg[(rg+i)*256 + c];
      macc[i] = fmaf(v.x,w0,macc[i]); macc[i] = fmaf(v.y,w1,macc[i]);
      macc[i] = fmaf(v.z,w2,macc[i]); macc[i] = fmaf(v.w,w3,macc[i]);
    }
  }
#pragma unroll
  for (int i=0;i<8;i++) msgL[(rg+i)*128 + d] = macc[i] * rsL[rg+i];
  __syncthreads();

  if constexpr (MODE == 0){
    if (t < 128){
      float p = 0.f;
#pragma unroll
      for (int r=0;r<16;r++) p += msgL[r*128 + t] * scores[(size_t)(e0+r)*128 + t];
      partial[g*128 + t] = p;
    }
  } else if constexpr (MODE == 1){
#pragma unroll
    for (int i=0;i<8;i++)
      edge_out[(size_t)(e0+rg+i)*128 + d] += msgL[(rg+i)*128 + d];
  } else {
    float eacc[8];
#pragma unroll
    for (int i=0;i<8;i++) eacc[i]=0.f;
    for (int dd=0; dd<128; dd++){
      float w = eproj[dd*128 + d];
#pragma unroll
      for (int i=0;i<8;i++) eacc[i] = fmaf(msgL[(rg+i)*128 + dd], w, eacc[i]);
    }
#pragma unroll
    for (int i=0;i<8;i++)
      edge_out[(size_t)(e0+rg+i)*128 + d] += eacc[i];
    if (t < 128){
      float p = 0.f;
#pragma unroll
      for (int r=0;r<16;r++)
        p += msgL[r*128 + t] * env[(size_t)(e0+r)*128 + t] * sw[e0 + r];
      partial[g*128 + t] = p;
    }
  }
}

// node += sum of 4 partials per node
__global__ void node_add4_kernel(const float* __restrict__ partial, float* __restrict__ node_out){
  int n = blockIdx.x, t = threadIdx.x;
  node_out[n*128 + t] += partial[(4*n)*128+t] + partial[(4*n+1)*128+t]
                       + partial[(4*n+2)*128+t] + partial[(4*n+3)*128+t];
}

__global__ void node_final4_kernel(const float* __restrict__ partial,
                                   const float* __restrict__ nproj,
                                   float* __restrict__ node_out){
  __shared__ float seg[128];
  int n = blockIdx.x, t = threadIdx.x;
  seg[t] = partial[(4*n)*128+t] + partial[(4*n+1)*128+t]
         + partial[(4*n+2)*128+t] + partial[(4*n+3)*128+t];
  __syncthreads();
  float acc = 0.f;
  for (int dd=0; dd<128; dd++) acc = fmaf(seg[dd], nproj[dd*128 + t], acc);
  node_out[n*128 + t] += acc * E_SCALE_C;
}

// ---------------- launch ----------------
extern "C" void kernel_launch(void* const* d_in, const int* in_sizes, int n_in,
                              void* d_out, int out_size, void* d_ws, size_t ws_size,
                              hipStream_t stream){
  const float* node_in  = (const float*)d_in[0];
  const float* edge_in  = (const float*)d_in[1];
  const float* angle_in = (const float*)d_in[2];
  const float* sw       = (const float*)d_in[3];
  const float* a_sw     = (const float*)d_in[4];
  const float* rbf      = (const float*)d_in[5];
  const int*   edge_index = (const int*)d_in[6];
  const float* la_norm_e = (const float*)d_in[8];
  const float* la_norm_a = (const float*)d_in[9];
  const float* la_win    = (const float*)d_in[10];
  const float* la_nw     = (const float*)d_in[11];
  const float* la_wout   = (const float*)d_in[12];
  const float* la_gate   = (const float*)d_in[13];
  const float* aa_norm_n = (const float*)d_in[14];
  const float* aa_norm_e = (const float*)d_in[15];
  const float* aa_win    = (const float*)d_in[16];
  const float* aa_nw     = (const float*)d_in[17];
  const float* aa_wout   = (const float*)d_in[18];
  const float* aa_src_gate = (const float*)d_in[19];
  const float* ae_win    = (const float*)d_in[20];
  const float* ae_nw     = (const float*)d_in[21];
  const float* ae_wout   = (const float*)d_in[22];
  const float* lr_norm_e = (const float*)d_in[23];
  const float* lr_norm_a = (const float*)d_in[24];
  const float* lr_win    = (const float*)d_in[25];
  const float* lr_nw     = (const float*)d_in[26];
  const float* lr_wout   = (const float*)d_in[27];
  const float* lr_env    = (const float*)d_in[28];
  const float* lr_eproj  = (const float*)d_in[29];
  const float* lr_aproj  = (const float*)d_in[30];
  const float* ar_norm_n = (const float*)d_in[31];
  const float* ar_norm_e = (const float*)d_in[32];
  const float* ar_win    = (const float*)d_in[33];
  const float* ar_nw     = (const float*)d_in[34];
  const float* ar_wout   = (const float*)d_in[35];
  const float* ar_env    = (const float*)d_in[36];
  const float* ar_nproj  = (const float*)d_in[37];
  const float* ar_eproj  = (const float*)d_in[38];

  float* out_node  = (float*)d_out;
  float* out_edge  = out_node + 128*128;
  float* out_angle = out_edge + (size_t)8192*128;

  // workspace carve (floats; bf16 buffers use 2 elems/float)
  float* p = (float*)d_ws;
  float* Pc_f    = p; p += 5898240;   // bf16 [18432][640] chunk buffer
  float* hat_f   = p; p += 2359296;   // bf16 [73728][64]
  float* preE_f  = p; p += 1966080;   // bf16 [3072][1280] (blk3 uses [3072][1024])
  float* He_f    = p; p += 4718592;   // bf16 [8192][1152] (blk4 [8192][512])
  float* enc_f   = p; p += 196608;    // bf16 [3072][128]
  float* enf_f   = p; p += 524288;    // bf16 [8192][128]
  float* wang_f  = p; p += 36864;     // bf16 [1152][64]
  float* we1_f   = p; p += 81920;     // bf16 [1280][128]
  float* we3_f   = p; p += 65536;     // bf16 [1024][128]
  float* whe2_f  = p; p += 73728;     // bf16 [1152][128]
  float* whe4_f  = p; p += 32768;     // bf16 [512][128]
  float* np1     = p; p += 81920;     // fp32 [128][640]
  float* np3     = p; p += 65536;     // fp32 [128][512]
  float* npa     = p; p += 131072;    // fp32 [128][1024]
  float* npe     = p; p += 131072;
  float* npr     = p; p += 131072;
  float* n_n     = p; p += 16384;
  float* wo_la   = p; p += 32768;
  float* wo_aa   = p; p += 32768;
  float* wo_ae   = p; p += 32768;
  float* wo_lr   = p; p += 32768;
  float* wo_ar   = p; p += 32768;
  float* scores2 = p; p += 1048576;
  float* env     = p; p += 1048576;
  float* partial = p; p += 65536;     // [512][128]

  u16* Pc   = (u16*)Pc_f;
  u16* hat  = (u16*)hat_f;
  u16* preE = (u16*)preE_f;
  u16* He   = (u16*)He_f;
  u16* enc  = (u16*)enc_f;
  u16* enf  = (u16*)enf_f;
  u16* wang = (u16*)wang_f;
  u16* we1  = (u16*)we1_f;
  u16* we3  = (u16*)we3_f;
  u16* whe2 = (u16*)whe2_f;
  u16* whe4 = (u16*)whe4_f;

  dim3 b256(256), b128(128);
  const int* next2e = edge_index + 8192;
  #define WT(src, ld, row0, scale, dst, c0, C, klog) \
    build_wt_kernel<<<((C << klog)+255)/256, b256, 0, stream>>>(src, ld, row0, scale, dst, c0, (C << klog), klog)

  // ---- prep ----
  scale_wout_kernel<<<128, b256, 0, stream>>>(la_wout, la_nw, wo_la);
  scale_wout_kernel<<<128, b256, 0, stream>>>(aa_wout, aa_nw, wo_aa);
  scale_wout_kernel<<<128, b256, 0, stream>>>(ae_wout, ae_nw, wo_ae);
  scale_wout_kernel<<<128, b256, 0, stream>>>(lr_wout, lr_nw, wo_lr);
  scale_wout_kernel<<<128, b256, 0, stream>>>(ar_wout, ar_nw, wo_ar);
  WT(la_win, 512, 0, la_norm_a, wang, 0,   512, 6);
  WT(la_gate,128, 0, la_norm_a, wang, 512, 128, 6);
  WT(lr_win, 512, 0, lr_norm_a, wang, 640, 512, 6);
  WT(la_win, 512, 192, nullptr, we1, 0,    512, 7);
  WT(la_win, 512, 320, nullptr, we1, 512,  512, 7);
  WT(la_gate,128, 192, nullptr, we1, 1024, 128, 7);
  WT(la_gate,128, 320, nullptr, we1, 1152, 128, 7);
  WT(lr_win, 512, 192, nullptr, we3, 0,    512, 7);
  WT(lr_win, 512, 320, nullptr, we3, 512,  512, 7);
  WT(aa_win, 512, 0,   nullptr, whe2, 0,   512, 7);
  WT(ae_win, 512, 0,   nullptr, whe2, 512, 512, 7);
  WT(aa_src_gate,128,0,nullptr, whe2, 1024,128, 7);
  WT(ar_win, 512, 0,   nullptr, whe4, 0,   512, 7);
  rmsnorm64_hat_kernel<<<18432, b256, 0, stream>>>(angle_in, hat);
  copy4_kernel<<<1024, b256, 0, stream>>>((const float4*)edge_in, (float4*)out_edge, 262144);
  copy4_kernel<<<16,   b256, 0, stream>>>((const float4*)node_in, (float4*)out_node, 4096);

  // ---- block 1 ----
  rmsnorm128c_bf16_kernel<<<768, b256, 0, stream>>>(edge_in, la_norm_e, enc);
  gemm_bf16_kernel<<<dim3(96,10), b256, 0, stream>>>(enc, we1, preE, 1280, 128);
  node_gemm_kernel<<<dim3(128,4), b128, 0, stream>>>(node_in, la_win, 512, 64, np1, 640, 0);
  node_gemm_kernel<<<dim3(128,1), b128, 0, stream>>>(node_in, la_gate,128, 64, np1, 640, 512);
  for (int c=0;c<4;c++){
    gemm_bf16_kernel<<<dim3(576,5), b256, 0, stream>>>(hat + (size_t)c*18432*64, wang, Pc, 640, 64);
    angle_fused_kernel<true><<<768, b256, 0, stream>>>(angle_in, Pc, preE, np1, wo_la,
        nullptr, nullptr, nullptr, nullptr, out_edge, nullptr, c*32);
  }

  // ---- block 2 ----
  rmsnorm128_bf16_kernel<<<2048, b256, 0, stream>>>(out_edge, aa_norm_e, enf, 8192);
  rmsnorm128_kernel<<<32, b256, 0, stream>>>(node_in, aa_norm_n, n_n, 128);
  gemm_bf16_kernel<<<dim3(256,9), b256, 0, stream>>>(enf, whe2, He, 1152, 128);
  node_gemm_kernel<<<dim3(128,4), b128, 0, stream>>>(n_n, aa_win, 512, 128, npa, 1024, 0);
  node_gemm_kernel<<<dim3(128,4), b128, 0, stream>>>(n_n, aa_win, 512, 256, npa, 1024, 512);
  node_gemm_kernel<<<dim3(128,4), b128, 0, stream>>>(n_n, ae_win, 512, 128, npe, 1024, 0);
  node_gemm_kernel<<<dim3(128,4), b128, 0, stream>>>(n_n, ae_win, 512, 256, npe, 1024, 512);
  scores_kernel<<<128, b256, 0, stream>>>(He, scores2);
  edge_fused_kernel<0><<<512, b256, 0, stream>>>(He, 1152, 0, npa, next2e, wo_aa,
      scores2, nullptr, nullptr, nullptr, nullptr, partial);
  edge_fused_kernel<1><<<512, b256, 0, stream>>>(He, 1152, 512, npe, next2e, wo_ae,
      nullptr, nullptr, nullptr, nullptr, out_edge, nullptr);
  node_add4_kernel<<<128, b128, 0, stream>>>(partial, out_node);

  // ---- block 3 ----
  rmsnorm128c_bf16_kernel<<<768, b256, 0, stream>>>(out_edge, lr_norm_e, enc);
  gemm_bf16_kernel<<<dim3(96,8), b256, 0, stream>>>(enc, we3, preE, 1024, 128);
  node_gemm_kernel<<<dim3(128,4), b128, 0, stream>>>(out_node, lr_win, 512, 64, np3, 512, 0);
  env_kernel<<<4096, b256, 0, stream>>>(rbf, lr_env, env);
  for (int c=0;c<4;c++){
    gemm_bf16_kernel<<<dim3(576,4), b256, 0, stream>>>(hat + (size_t)c*18432*64, wang + 640*64, Pc, 512, 64);
    angle_fused_kernel<false><<<768, b256, 0, stream>>>(angle_in, Pc, preE, np3, wo_lr,
        env, a_sw, lr_aproj, lr_eproj, out_edge, out_angle, c*32);
  }

  // ---- block 4 ----
  rmsnorm128_bf16_kernel<<<2048, b256, 0, stream>>>(out_edge, ar_norm_e, enf, 8192);
  rmsnorm128_kernel<<<32, b256, 0, stream>>>(out_node, ar_norm_n, n_n, 128);
  gemm_bf16_kernel<<<dim3(256,4), b256, 0, stream>>>(enf, whe4, He, 512, 128);
  node_gemm_kernel<<<dim3(128,4), b128, 0, stream>>>(n_n, ar_win, 512, 128, npr, 1024, 0);
  node_gemm_kernel<<<dim3(128,4), b128, 0, stream>>>(n_n, ar_win, 512, 256, npr, 1024, 512);
  env_kernel<<<4096, b256, 0, stream>>>(rbf, ar_env, env);
  edge_fused_kernel<2><<<512, b256, 0, stream>>>(He, 512, 0, npr, next2e, wo_ar,
      nullptr, env, sw, ar_eproj, out_edge, partial);
  node_final4_kernel<<<128, b128, 0, stream>>>(partial, ar_nproj, out_node);

  (void)in_sizes; (void)n_in; (void)out_size; (void)ws_size;
}

// Round 3
// 605.823 us; speedup vs baseline: 3.2520x; 1.3323x over previous
//
#include <hip/hip_runtime.h>

#define A_SCALE_C 0.6454972243679028f   // (24/10)^-0.5
#define E_SCALE_C 0.3952847075210474f   // (64/10)^-0.5

typedef unsigned short u16;
typedef unsigned int u32;
typedef __attribute__((ext_vector_type(8))) short bf16x8;
typedef __attribute__((ext_vector_type(4))) float f32x4;

static __device__ __forceinline__ float waveSum(float v){
#pragma unroll
  for (int off = 32; off; off >>= 1) v += __shfl_xor(v, off, 64);
  return v;
}
static __device__ __forceinline__ float silu(float g){
  return g / (1.0f + __expf(-g));
}
static __device__ __forceinline__ float bf2f(u16 h){
  union { u32 u; float f; } x; x.u = ((u32)h) << 16; return x.f;
}
static __device__ __forceinline__ u16 f2bf(float f){
  union { float f; u32 u; } x; x.f = f;
  u32 r = x.u + 0x7FFFu + ((x.u >> 16) & 1u);
  return (u16)(r >> 16);
}

// ---------------- small prep kernels ----------------

__global__ void scale_wout_kernel(const float* __restrict__ w, const float* __restrict__ nw,
                                  float* __restrict__ out){
  int idx = blockIdx.x*256 + threadIdx.x;
  out[idx] = w[idx] * nw[idx >> 7];
}

__global__ void copy4_kernel(const float4* __restrict__ src, float4* __restrict__ dst, int n4){
  int idx = blockIdx.x*256 + threadIdx.x;
  if (idx < n4) dst[idx] = src[idx];
}

// dst[(c0+c)*K + k] = bf16(src[(row0+k)*src_ld + c] * scale[k])
__global__ void build_wt_kernel(const float* __restrict__ src, int src_ld, int row0,
                                const float* __restrict__ rowscale,
                                u16* __restrict__ dst, int c0, int total, int klog){
  int idx = blockIdx.x*256 + threadIdx.x;
  if (idx >= total) return;
  int K = 1 << klog;
  int c = idx >> klog, k = idx & (K-1);
  float s = rowscale ? rowscale[k] : 1.0f;
  dst[(size_t)(c0+c)*K + k] = f2bf(src[(size_t)(row0+k)*src_ld + c] * s);
}

// angle_hat bf16 (rmsnorm over 64 dims, no weight)
__global__ void rmsnorm64_hat_kernel(const float* __restrict__ ang, u16* __restrict__ hat){
  int row = blockIdx.x*4 + (threadIdx.x >> 6);
  int lane = threadIdx.x & 63;
  float x = ang[(size_t)row*64 + lane];
  float ss = waveSum(x*x);
  float rs = rsqrtf(ss*(1.0f/64.0f) + 1e-6f);
  hat[(size_t)row*64 + lane] = f2bf(x*rs);
}

__global__ void rmsnorm128_bf16_kernel(const float* __restrict__ x, const float* __restrict__ w,
                                       u16* __restrict__ out, int nrows){
  int row = blockIdx.x*4 + (threadIdx.x >> 6);
  int lane = threadIdx.x & 63;
  if (row >= nrows) return;
  float2 v = *(const float2*)(x + (size_t)row*128 + lane*2);
  float ss = waveSum(v.x*v.x + v.y*v.y);
  float rs = rsqrtf(ss*(1.0f/128.0f) + 1e-6f);
  float2 wv = *(const float2*)(w + lane*2);
  u32 pk = (u32)f2bf(v.x*rs*wv.x) | ((u32)f2bf(v.y*rs*wv.y) << 16);
  *(u32*)(out + (size_t)row*128 + lane*2) = pk;
}

// compact rmsnorm: 3072 used-edge rows (loc*64+j, j<24) -> bf16
__global__ void rmsnorm128c_bf16_kernel(const float* __restrict__ x, const float* __restrict__ w,
                                        u16* __restrict__ out){
  int row = blockIdx.x*4 + (threadIdx.x >> 6);   // 0..3071
  int lane = threadIdx.x & 63;
  int src = (row/24)*64 + row%24;
  float2 v = *(const float2*)(x + (size_t)src*128 + lane*2);
  float ss = waveSum(v.x*v.x + v.y*v.y);
  float rs = rsqrtf(ss*(1.0f/128.0f) + 1e-6f);
  float2 wv = *(const float2*)(w + lane*2);
  u32 pk = (u32)f2bf(v.x*rs*wv.x) | ((u32)f2bf(v.y*rs*wv.y) << 16);
  *(u32*)(out + (size_t)row*128 + lane*2) = pk;
}

__global__ void rmsnorm128_kernel(const float* __restrict__ x, const float* __restrict__ w,
                                  float* __restrict__ out, int nrows){
  int row = blockIdx.x*4 + (threadIdx.x >> 6);
  int lane = threadIdx.x & 63;
  if (row >= nrows) return;
  float2 v = *(const float2*)(x + (size_t)row*128 + lane*2);
  float ss = waveSum(v.x*v.x + v.y*v.y);
  float rs = rsqrtf(ss*(1.0f/128.0f) + 1e-6f);
  float2 wv = *(const float2*)(w + lane*2);
  float2 o; o.x = v.x*rs*wv.x; o.y = v.y*rs*wv.y;
  *(float2*)(out + (size_t)row*128 + lane*2) = o;
}

__global__ __launch_bounds__(256) void env_kernel(const float* __restrict__ rbf,
                                                  const float* __restrict__ w,
                                                  float* __restrict__ env){
  __shared__ float wL[12*128];
  int t = threadIdx.x;
  for (int idx=t; idx<12*128; idx+=256) wL[idx] = w[idx];
  __syncthreads();
  int base = blockIdx.x*256 + t;
  int e = base >> 7, d = base & 127;
  float acc = 0.f;
#pragma unroll
  for (int k=0;k<12;k++) acc = fmaf(rbf[e*12+k], wL[k*128+d], acc);
  env[base] = acc;
}

// node tables: C[row][c_off+col] = sum_k A[row][k] * B[(b_row0+k)*b_ld + col]
__global__ __launch_bounds__(128) void node_gemm_kernel(const float* __restrict__ A,
    const float* __restrict__ B, int b_ld, int b_row0,
    float* __restrict__ C, int c_ld, int c_off){
  __shared__ float ar[128];
  int row = blockIdx.x, t = threadIdx.x;
  ar[t] = A[row*128 + t];
  __syncthreads();
  int col = blockIdx.y*128 + t;
  float acc = 0.f;
  for (int k=0;k<128;k++) acc = fmaf(ar[k], B[(size_t)(b_row0+k)*b_ld + col], acc);
  C[(size_t)row*c_ld + c_off + col] = acc;
}

// ---------------- MFMA GEMM: C[M][N]bf16 = A[M][K]bf16 @ Bt[N][K]^T ----------------
__global__ __launch_bounds__(256) void gemm_bf16_kernel(
    const u16* __restrict__ A, const u16* __restrict__ Bt, u16* __restrict__ C,
    int N, int K){
  __shared__ float cl[32*128];
  const int lane = threadIdx.x & 63, wave = threadIdx.x >> 6;
  const size_t arow = (size_t)blockIdx.x*32;
  const size_t bcol = (size_t)blockIdx.y*128 + wave*32;
  f32x4 acc00={0,0,0,0}, acc01={0,0,0,0}, acc10={0,0,0,0}, acc11={0,0,0,0};
  for (int k=0; k<K; k+=32){
    int ko = k + (lane>>4)*8;
    bf16x8 a0 = *(const bf16x8*)(A + (arow + (lane&15))*K + ko);
    bf16x8 a1 = *(const bf16x8*)(A + (arow + 16 + (lane&15))*K + ko);
    bf16x8 b0 = *(const bf16x8*)(Bt + (bcol + (lane&15))*K + ko);
    bf16x8 b1 = *(const bf16x8*)(Bt + (bcol + 16 + (lane&15))*K + ko);
    acc00 = __builtin_amdgcn_mfma_f32_16x16x32_bf16(a0, b0, acc00, 0,0,0);
    acc01 = __builtin_amdgcn_mfma_f32_16x16x32_bf16(a0, b1, acc01, 0,0,0);
    acc10 = __builtin_amdgcn_mfma_f32_16x16x32_bf16(a1, b0, acc10, 0,0,0);
    acc11 = __builtin_amdgcn_mfma_f32_16x16x32_bf16(a1, b1, acc11, 0,0,0);
  }
  const int cr = (lane>>4)*4, cc = wave*32 + (lane&15);
#pragma unroll
  for (int q=0;q<4;q++){
    cl[(cr+q)*128 + cc]      = acc00[q];
    cl[(cr+q)*128 + cc+16]   = acc01[q];
    cl[(16+cr+q)*128 + cc]    = acc10[q];
    cl[(16+cr+q)*128 + cc+16] = acc11[q];
  }
  __syncthreads();
  const int t = threadIdx.x;
  size_t base = arow*N + (size_t)blockIdx.y*128;
#pragma unroll
  for (int i=0;i<16;i++){
    int idx = i*256 + t; int r = idx>>7, c = idx&127;
    C[base + (size_t)r*N + c] = f2bf(cl[idx]);
  }
}

// ---------------- fused angle kernel with in-kernel MFMA (blocks 1 and 3) ----------------
// one workgroup = one eij segment (24 angle rows). grid 3072, 256 threads (4 waves).
// hidden[24][HW] = [hat|enc_ik] @ [wangT|wikT]  (MFMA, K=192)  + preE_ij[seg] + NP[loc]
// msg[24][128]   = bf16(vg) @ woT (MFMA, K=256), rms scale applied after.
template<bool IS_BLK1>
__global__ __launch_bounds__(256) void angle_mfma_kernel(
    const u16* __restrict__ hat,      // [73728][64]
    const u16* __restrict__ enc,      // [3072][128]
    const u16* __restrict__ wangT,    // [HW][64]  (la_norm_a folded)
    const u16* __restrict__ wikT,     // [HW][128]
    const u16* __restrict__ preE,     // [3072][HW]
    const float* __restrict__ NP,     // [128][HW]
    const u16* __restrict__ woT,      // [128][256] (nw folded)
    const float* __restrict__ angle,
    const float* __restrict__ env, const float* __restrict__ a_sw,
    const float* __restrict__ aproj, const float* __restrict__ eproj,
    float* __restrict__ edge_out, float* __restrict__ angle_out)
{
  constexpr int HW = IS_BLK1 ? 640 : 512;
  constexpr int NT = IS_BLK1 ? 10 : 8;
  constexpr int GA = IS_BLK1 ? 16896 : 0;
  __shared__ __align__(16) char ldsRaw[(IS_BLK1 ? 34944 : 18048)];
  u16*   vgn   = (u16*)ldsRaw;                    // [32][264] bf16 (unnormalized vg)
  float* gateL = (float*)(ldsRaw + 16896);        // blk1 [24][132]
  float* ssL   = (float*)(ldsRaw + 16896 + GA);   // [4][32]
  float* segL  = (float*)(ldsRaw + 17408 + GA);   // [128]
  float* rsL   = (float*)(ldsRaw + 17920 + GA);   // [32]
  float* msgL  = (float*)ldsRaw;                  // alias vgn after out-GEMM: [32][132]

  const int t = threadIdx.x, lane = t & 63, w = t >> 6;
  const int l15 = lane & 15, l4 = lane >> 4;
  const int seg = blockIdx.x;
  const int loc = seg / 24, j = seg - loc*24;
  const int loc24 = loc*24;
  const int eij = loc*64 + j;

  // ---- hidden MFMA: K=192 ([hat 64 | enc_ik 128]) ----
  f32x4 acc[2][NT];
#pragma unroll
  for (int m=0;m<2;m++)
#pragma unroll
    for (int nt=0;nt<NT;nt++) acc[m][nt] = (f32x4){0.f,0.f,0.f,0.f};

  int hr0 = seg*24 + l15;            // < 73728 always (l15<16<24)
  int hr1 = seg*24 + 16 + l15;  if (hr1 > 73727) hr1 = 73727;   // rows>=24 garbage, zeroed later
  int er0 = loc24 + l15;
  int er1 = loc24 + 16 + l15;   if (er1 > 3071) er1 = 3071;

#pragma unroll
  for (int kk=0; kk<6; kk++){
    bf16x8 a0, a1;
    if (kk < 2){
      a0 = *(const bf16x8*)(hat + (size_t)hr0*64 + kk*32 + l4*8);
      a1 = *(const bf16x8*)(hat + (size_t)hr1*64 + kk*32 + l4*8);
    } else {
      a0 = *(const bf16x8*)(enc + (size_t)er0*128 + (kk-2)*32 + l4*8);
      a1 = *(const bf16x8*)(enc + (size_t)er1*128 + (kk-2)*32 + l4*8);
    }
#pragma unroll
    for (int nt=0; nt<NT; nt++){
      int col0 = (nt<4) ? (w*64 + nt*16) : ((nt<8) ? (256 + w*64 + (nt-4)*16)
                                                   : (512 + w*32 + (nt-8)*16));
      const u16* bp = (kk<2) ? (wangT + (size_t)(col0+l15)*64  + kk*32 + l4*8)
                             : (wikT  + (size_t)(col0+l15)*128 + (kk-2)*32 + l4*8);
      bf16x8 b = *(const bf16x8*)bp;
      acc[0][nt] = __builtin_amdgcn_mfma_f32_16x16x32_bf16(a0, b, acc[0][nt], 0,0,0);
      acc[1][nt] = __builtin_amdgcn_mfma_f32_16x16x32_bf16(a1, b, acc[1][nt], 0,0,0);
    }
  }

  // ---- add preE_ij + NP, silu, write unnormalized vg (bf16) + row ss ----
  float ss[2][4] = {{0,0,0,0},{0,0,0,0}};
#pragma unroll
  for (int vt=0; vt<4; vt++){
    int cv = w*64 + vt*16 + l15;
    float pv = bf2f(preE[(size_t)seg*HW + cv])       + NP[(size_t)loc*HW + cv];
    float pg = bf2f(preE[(size_t)seg*HW + 256 + cv]) + NP[(size_t)loc*HW + 256 + cv];
#pragma unroll
    for (int m=0;m<2;m++){
#pragma unroll
      for (int q=0;q<4;q++){
        int r = m*16 + l4*4 + q;
        float v = acc[m][vt][q] + pv;
        float g = acc[m][4+vt][q] + pg;
        float x = (r < 24) ? v * silu(g) : 0.f;
        ss[m][q] += x*x;
        vgn[r*264 + cv] = f2bf(x);
      }
    }
  }
#pragma unroll
  for (int m=0;m<2;m++)
#pragma unroll
    for (int q=0;q<4;q++){
      float s = ss[m][q];
      s += __shfl_xor(s,1,64); s += __shfl_xor(s,2,64);
      s += __shfl_xor(s,4,64); s += __shfl_xor(s,8,64);
      if (l15 == 0) ssL[w*32 + m*16 + l4*4 + q] = s;
    }
  if constexpr (IS_BLK1){
#pragma unroll
    for (int gt=0; gt<2; gt++){
      int cg = w*32 + gt*16 + l15;
      float pgt = bf2f(preE[(size_t)seg*HW + 512 + cg]) + NP[(size_t)loc*HW + 512 + cg];
#pragma unroll
      for (int m=0;m<2;m++)
#pragma unroll
        for (int q=0;q<4;q++){
          int r = m*16 + l4*4 + q;
          if (r < 24) gateL[r*132 + cg] = (acc[m][8+gt][q] + pgt) * A_SCALE_C;
        }
    }
  }
  __syncthreads();
  if (t < 32){
    float s_ = ssL[t] + ssL[32+t] + ssL[64+t] + ssL[96+t];
    rsL[t] = rsqrtf(s_*(1.0f/256.0f) + 1e-6f);
  }
  __syncthreads();

  // ---- out-GEMM MFMA: msg = vg @ woT, K=256 ----
  f32x4 mac[2][2];
#pragma unroll
  for (int m=0;m<2;m++){ mac[m][0]=(f32x4){0,0,0,0}; mac[m][1]=(f32x4){0,0,0,0}; }
#pragma unroll
  for (int kk=0; kk<8; kk++){
    bf16x8 a0 = *(const bf16x8*)&vgn[l15*264      + kk*32 + l4*8];
    bf16x8 a1 = *(const bf16x8*)&vgn[(16+l15)*264 + kk*32 + l4*8];
#pragma unroll
    for (int nt=0; nt<2; nt++){
      int oc = w*32 + nt*16 + l15;
      bf16x8 b = *(const bf16x8*)(woT + (size_t)oc*256 + kk*32 + l4*8);
      mac[0][nt] = __builtin_amdgcn_mfma_f32_16x16x32_bf16(a0, b, mac[0][nt], 0,0,0);
      mac[1][nt] = __builtin_amdgcn_mfma_f32_16x16x32_bf16(a1, b, mac[1][nt], 0,0,0);
    }
  }
  float rsv[2][4];
#pragma unroll
  for (int m=0;m<2;m++)
#pragma unroll
    for (int q=0;q<4;q++) rsv[m][q] = rsL[m*16 + l4*4 + q];
  __syncthreads();   // all vgn reads done; safe to alias msgL
#pragma unroll
  for (int m=0;m<2;m++)
#pragma unroll
    for (int nt=0;nt<2;nt++)
#pragma unroll
      for (int q=0;q<4;q++)
        msgL[(m*16 + l4*4 + q)*132 + w*32 + nt*16 + l15] = mac[m][nt][q] * rsv[m][q];
  __syncthreads();

  // ---- epilogue ----
  if constexpr (IS_BLK1){
    if (t < 128){
      float ex[24]; float mx = -1e30f;
#pragma unroll
      for (int r=0;r<24;r++){ ex[r] = gateL[r*132 + t]; mx = fmaxf(mx, ex[r]); }
      float S = 0.f;
#pragma unroll
      for (int r=0;r<24;r++){ ex[r] = __expf(ex[r] - mx); S += ex[r]; }
      float inv = 1.f/(S + 1e-12f);
      float delta = 0.f;
#pragma unroll
      for (int r=0;r<24;r++) delta += msgL[r*132 + t] * ex[r];
      edge_out[(size_t)eij*128 + t] += delta * inv;
    }
  } else {
    {
      const int c = t & 63, ra = (t >> 6) * 6;
      float aacc[6] = {0,0,0,0,0,0};
      for (int dd=0; dd<128; dd++){
        float wv = aproj[dd*64 + c];
#pragma unroll
        for (int i=0;i<6;i++) aacc[i] = fmaf(msgL[(ra+i)*132 + dd], wv, aacc[i]);
      }
      const size_t a0 = (size_t)seg*24;
#pragma unroll
      for (int i=0;i<6;i++){
        size_t a = a0 + ra + i;
        angle_out[a*64 + c] = angle[a*64 + c] + aacc[i] * a_sw[a];
      }
    }
    if (t < 128){
      const size_t a0 = (size_t)seg*24;
      float sg_ = 0.f;
#pragma unroll
      for (int r=0;r<24;r++)
        sg_ += msgL[r*132 + t] * env[(size_t)(loc*64 + r)*128 + t] * a_sw[a0 + r];
      segL[t] = sg_;
    }
    __syncthreads();
    if (t < 128){
      float acc2 = 0.f;
      for (int dd=0; dd<128; dd++) acc2 = fmaf(segL[dd], eproj[dd*128 + t], acc2);
      edge_out[(size_t)eij*128 + t] += acc2 * A_SCALE_C;
    }
  }
}

// blk2 per-dim softmax over each node's 64 edges; gate from He cols 1024..1151
__global__ __launch_bounds__(256) void scores_kernel(const u16* __restrict__ He,
                                                     float* __restrict__ scores){
  __shared__ float s[64*128];
  const int t = threadIdx.x, n = blockIdx.x;
  for (int idx=t; idx<64*128; idx+=256){
    int r = idx>>7, c = idx&127;
    s[idx] = bf2f(He[(size_t)(n*64+r)*1152 + 1024 + c]) * E_SCALE_C;
  }
  __syncthreads();
  if (t < 128){
    float m = -1e30f;
    for (int r=0;r<64;r++) m = fmaxf(m, s[r*128 + t]);
    float S = 0.f;
    for (int r=0;r<64;r++) S += __expf(s[r*128 + t] - m);
    float inv = 1.f/(S + 1e-12f);
    for (int r=0;r<64;r++)
      scores[(size_t)(n*64 + r)*128 + t] = __expf(s[r*128 + t] - m) * inv;
  }
}

// ---------------- fused edge kernel (blocks 2 and 4) ----------------
template<int MODE>
__global__ __launch_bounds__(256) void edge_fused_kernel(
    const u16* __restrict__ He, int he_ld, int he_off,
    const float* __restrict__ NPt,      // [128][1024] self(512)|nbr(512)
    const int* __restrict__ next2e,
    const float* __restrict__ wout,
    const float* __restrict__ scores, const float* __restrict__ env,
    const float* __restrict__ sw, const float* __restrict__ eproj,
    float* __restrict__ edge_out, float* __restrict__ partial){
  __shared__ float vg[16*256];
  __shared__ float msgL[16*128];
  __shared__ float rsL[16];
  __shared__ int nxL[16];
  const int t = threadIdx.x, g = blockIdx.x, e0 = g*16, n = e0 >> 6;
  if (t < 16) nxL[t] = next2e[e0 + t];
  __syncthreads();
  float bv = NPt[n*1024 + t], bg = NPt[n*1024 + 256 + t];
  for (int r=0;r<16;r++){
    int nx = nxL[r];
    float v  = bf2f(He[(size_t)(e0+r)*he_ld + he_off + t])       + bv + NPt[nx*1024 + 512 + t];
    float gg = bf2f(He[(size_t)(e0+r)*he_ld + he_off + 256 + t]) + bg + NPt[nx*1024 + 768 + t];
    vg[r*256 + t] = v * silu(gg);
  }
  __syncthreads();
  {
    const int wv = t >> 6, lane = t & 63;
    for (int r=wv; r<16; r+=4){
      const float4 v = *(const float4*)&vg[r*256 + lane*4];
      float ss = waveSum(v.x*v.x + v.y*v.y + v.z*v.z + v.w*v.w);
      if (lane == 0) rsL[r] = rsqrtf(ss*(1.0f/256.0f) + 1e-6f);
    }
  }
  __syncthreads();
  const int d  = t & 127;
  const int rg = (t >> 7) * 8;
  float macc[8];
#pragma unroll
  for (int i=0;i<8;i++) macc[i]=0.f;
  for (int c=0;c<256;c+=4){
    float w0 = wout[(c+0)*128 + d];
    float w1 = wout[(c+1)*128 + d];
    float w2 = wout[(c+2)*128 + d];
    float w3 = wout[(c+3)*128 + d];
#pragma unroll
    for (int i=0;i<8;i++){
      const float4 v = *(const float4*)&vg[(rg+i)*256 + c];
      macc[i] = fmaf(v.x,w0,macc[i]); macc[i] = fmaf(v.y,w1,macc[i]);
      macc[i] = fmaf(v.z,w2,macc[i]); macc[i] = fmaf(v.w,w3,macc[i]);
    }
  }
#pragma unroll
  for (int i=0;i<8;i++) msgL[(rg+i)*128 + d] = macc[i] * rsL[rg+i];
  __syncthreads();

  if constexpr (MODE == 0){
    if (t < 128){
      float p = 0.f;
#pragma unroll
      for (int r=0;r<16;r++) p += msgL[r*128 + t] * scores[(size_t)(e0+r)*128 + t];
      partial[g*128 + t] = p;
    }
  } else if constexpr (MODE == 1){
#pragma unroll
    for (int i=0;i<8;i++)
      edge_out[(size_t)(e0+rg+i)*128 + d] += msgL[(rg+i)*128 + d];
  } else {
    float eacc[8];
#pragma unroll
    for (int i=0;i<8;i++) eacc[i]=0.f;
    for (int dd=0; dd<128; dd++){
      float wv = eproj[dd*128 + d];
#pragma unroll
      for (int i=0;i<8;i++) eacc[i] = fmaf(msgL[(rg+i)*128 + dd], wv, eacc[i]);
    }
#pragma unroll
    for (int i=0;i<8;i++)
      edge_out[(size_t)(e0+rg+i)*128 + d] += eacc[i];
    if (t < 128){
      float p = 0.f;
#pragma unroll
      for (int r=0;r<16;r++)
        p += msgL[r*128 + t] * env[(size_t)(e0+r)*128 + t] * sw[e0 + r];
      partial[g*128 + t] = p;
    }
  }
}

__global__ void node_add4_kernel(const float* __restrict__ partial, float* __restrict__ node_out){
  int n = blockIdx.x, t = threadIdx.x;
  node_out[n*128 + t] += partial[(4*n)*128+t] + partial[(4*n+1)*128+t]
                       + partial[(4*n+2)*128+t] + partial[(4*n+3)*128+t];
}

__global__ void node_final4_kernel(const float* __restrict__ partial,
                                   const float* __restrict__ nproj,
                                   float* __restrict__ node_out){
  __shared__ float seg[128];
  int n = blockIdx.x, t = threadIdx.x;
  seg[t] = partial[(4*n)*128+t] + partial[(4*n+1)*128+t]
         + partial[(4*n+2)*128+t] + partial[(4*n+3)*128+t];
  __syncthreads();
  float acc = 0.f;
  for (int dd=0; dd<128; dd++) acc = fmaf(seg[dd], nproj[dd*128 + t], acc);
  node_out[n*128 + t] += acc * E_SCALE_C;
}

// ---------------- launch ----------------
extern "C" void kernel_launch(void* const* d_in, const int* in_sizes, int n_in,
                              void* d_out, int out_size, void* d_ws, size_t ws_size,
                              hipStream_t stream){
  const float* node_in  = (const float*)d_in[0];
  const float* edge_in  = (const float*)d_in[1];
  const float* angle_in = (const float*)d_in[2];
  const float* sw       = (const float*)d_in[3];
  const float* a_sw     = (const float*)d_in[4];
  const float* rbf      = (const float*)d_in[5];
  const int*   edge_index = (const int*)d_in[6];
  const float* la_norm_e = (const float*)d_in[8];
  const float* la_norm_a = (const float*)d_in[9];
  const float* la_win    = (const float*)d_in[10];
  const float* la_nw     = (const float*)d_in[11];
  const float* la_wout   = (const float*)d_in[12];
  const float* la_gate   = (const float*)d_in[13];
  const float* aa_norm_n = (const float*)d_in[14];
  const float* aa_norm_e = (const float*)d_in[15];
  const float* aa_win    = (const float*)d_in[16];
  const float* aa_nw     = (const float*)d_in[17];
  const float* aa_wout   = (const float*)d_in[18];
  const float* aa_src_gate = (const float*)d_in[19];
  const float* ae_win    = (const float*)d_in[20];
  const float* ae_nw     = (const float*)d_in[21];
  const float* ae_wout   = (const float*)d_in[22];
  const float* lr_norm_e = (const float*)d_in[23];
  const float* lr_norm_a = (const float*)d_in[24];
  const float* lr_win    = (const float*)d_in[25];
  const float* lr_nw     = (const float*)d_in[26];
  const float* lr_wout   = (const float*)d_in[27];
  const float* lr_env    = (const float*)d_in[28];
  const float* lr_eproj  = (const float*)d_in[29];
  const float* lr_aproj  = (const float*)d_in[30];
  const float* ar_norm_n = (const float*)d_in[31];
  const float* ar_norm_e = (const float*)d_in[32];
  const float* ar_win    = (const float*)d_in[33];
  const float* ar_nw     = (const float*)d_in[34];
  const float* ar_wout   = (const float*)d_in[35];
  const float* ar_env    = (const float*)d_in[36];
  const float* ar_nproj  = (const float*)d_in[37];
  const float* ar_eproj  = (const float*)d_in[38];

  float* out_node  = (float*)d_out;
  float* out_edge  = out_node + 128*128;
  float* out_angle = out_edge + (size_t)8192*128;

  float* p = (float*)d_ws;
  float* hat_f   = p; p += 2359296;   // bf16 [73728][64]
  float* enc_f   = p; p += 196608;    // bf16 [3072][128]
  float* preE_f  = p; p += 983040;    // bf16 [3072][640] (blk3: [3072][512])
  float* He_f    = p; p += 4718592;   // bf16 [8192][1152]
  float* enf_f   = p; p += 524288;    // bf16 [8192][128]
  float* wang1_f = p; p += 20480;     // bf16 [640][64]
  float* wang3_f = p; p += 16384;     // bf16 [512][64]
  float* wik1_f  = p; p += 40960;     // bf16 [640][128]
  float* wik3_f  = p; p += 32768;     // bf16 [512][128]
  float* wij1_f  = p; p += 40960;     // bf16 [640][128]
  float* wij3_f  = p; p += 32768;     // bf16 [512][128]
  float* wo1T_f  = p; p += 16384;     // bf16 [128][256]
  float* wo3T_f  = p; p += 16384;     // bf16 [128][256]
  float* whe2_f  = p; p += 73728;     // bf16 [1152][128]
  float* whe4_f  = p; p += 32768;     // bf16 [512][128]
  float* NP1     = p; p += 81920;     // fp32 [128][640]
  float* NP3     = p; p += 65536;     // fp32 [128][512]
  float* npa     = p; p += 131072;    // fp32 [128][1024]
  float* npe     = p; p += 131072;
  float* npr     = p; p += 131072;
  float* n_n     = p; p += 16384;
  float* wo_aa   = p; p += 32768;
  float* wo_ae   = p; p += 32768;
  float* wo_ar   = p; p += 32768;
  float* scores2 = p; p += 1048576;
  float* env     = p; p += 1048576;
  float* partial = p; p += 65536;

  u16* hat  = (u16*)hat_f;
  u16* enc  = (u16*)enc_f;
  u16* preE = (u16*)preE_f;
  u16* He   = (u16*)He_f;
  u16* enf  = (u16*)enf_f;
  u16* wang1= (u16*)wang1_f;
  u16* wang3= (u16*)wang3_f;
  u16* wik1 = (u16*)wik1_f;
  u16* wik3 = (u16*)wik3_f;
  u16* wij1 = (u16*)wij1_f;
  u16* wij3 = (u16*)wij3_f;
  u16* wo1T = (u16*)wo1T_f;
  u16* wo3T = (u16*)wo3T_f;
  u16* whe2 = (u16*)whe2_f;
  u16* whe4 = (u16*)whe4_f;

  dim3 b256(256), b128(128);
  const int* next2e = edge_index + 8192;
  #define WT(src, ld, row0, scale, dst, c0, C, klog) \
    build_wt_kernel<<<((C << klog)+255)/256, b256, 0, stream>>>(src, ld, row0, scale, dst, c0, (C << klog), klog)

  // ---- prep ----
  scale_wout_kernel<<<128, b256, 0, stream>>>(aa_wout, aa_nw, wo_aa);
  scale_wout_kernel<<<128, b256, 0, stream>>>(ae_wout, ae_nw, wo_ae);
  scale_wout_kernel<<<128, b256, 0, stream>>>(ar_wout, ar_nw, wo_ar);
  WT(la_win, 512, 0,   la_norm_a, wang1, 0,   512, 6);
  WT(la_gate,128, 0,   la_norm_a, wang1, 512, 128, 6);
  WT(lr_win, 512, 0,   lr_norm_a, wang3, 0,   512, 6);
  WT(la_win, 512, 320, nullptr,   wik1, 0,    512, 7);
  WT(la_gate,128, 320, nullptr,   wik1, 512,  128, 7);
  WT(lr_win, 512, 320, nullptr,   wik3, 0,    512, 7);
  WT(la_win, 512, 192, nullptr,   wij1, 0,    512, 7);
  WT(la_gate,128, 192, nullptr,   wij1, 512,  128, 7);
  WT(lr_win, 512, 192, nullptr,   wij3, 0,    512, 7);
  WT(la_wout,128, 0,   la_nw,     wo1T, 0,    128, 8);
  WT(lr_wout,128, 0,   lr_nw,     wo3T, 0,    128, 8);
  WT(aa_win, 512, 0,   nullptr,   whe2, 0,    512, 7);
  WT(ae_win, 512, 0,   nullptr,   whe2, 512,  512, 7);
  WT(aa_src_gate,128,0,nullptr,   whe2, 1024, 128, 7);
  WT(ar_win, 512, 0,   nullptr,   whe4, 0,    512, 7);
  rmsnorm64_hat_kernel<<<18432, b256, 0, stream>>>(angle_in, hat);
  copy4_kernel<<<1024, b256, 0, stream>>>((const float4*)edge_in, (float4*)out_edge, 262144);
  copy4_kernel<<<16,   b256, 0, stream>>>((const float4*)node_in, (float4*)out_node, 4096);

  // ---- block 1 ----
  rmsnorm128c_bf16_kernel<<<768, b256, 0, stream>>>(edge_in, la_norm_e, enc);
  gemm_bf16_kernel<<<dim3(96,5), b256, 0, stream>>>(enc, wij1, preE, 640, 128);
  node_gemm_kernel<<<dim3(128,4), b128, 0, stream>>>(node_in, la_win, 512, 64, NP1, 640, 0);
  node_gemm_kernel<<<dim3(128,1), b128, 0, stream>>>(node_in, la_gate,128, 64, NP1, 640, 512);
  angle_mfma_kernel<true><<<3072, b256, 0, stream>>>(hat, enc, wang1, wik1, preE, NP1, wo1T,
      angle_in, nullptr, nullptr, nullptr, nullptr, out_edge, nullptr);

  // ---- block 2 ----
  rmsnorm128_bf16_kernel<<<2048, b256, 0, stream>>>(out_edge, aa_norm_e, enf, 8192);
  rmsnorm128_kernel<<<32, b256, 0, stream>>>(node_in, aa_norm_n, n_n, 128);
  gemm_bf16_kernel<<<dim3(256,9), b256, 0, stream>>>(enf, whe2, He, 1152, 128);
  node_gemm_kernel<<<dim3(128,4), b128, 0, stream>>>(n_n, aa_win, 512, 128, npa, 1024, 0);
  node_gemm_kernel<<<dim3(128,4), b128, 0, stream>>>(n_n, aa_win, 512, 256, npa, 1024, 512);
  node_gemm_kernel<<<dim3(128,4), b128, 0, stream>>>(n_n, ae_win, 512, 128, npe, 1024, 0);
  node_gemm_kernel<<<dim3(128,4), b128, 0, stream>>>(n_n, ae_win, 512, 256, npe, 1024, 512);
  scores_kernel<<<128, b256, 0, stream>>>(He, scores2);
  edge_fused_kernel<0><<<512, b256, 0, stream>>>(He, 1152, 0, npa, next2e, wo_aa,
      scores2, nullptr, nullptr, nullptr, nullptr, partial);
  edge_fused_kernel<1><<<512, b256, 0, stream>>>(He, 1152, 512, npe, next2e, wo_ae,
      nullptr, nullptr, nullptr, nullptr, out_edge, nullptr);
  node_add4_kernel<<<128, b128, 0, stream>>>(partial, out_node);

  // ---- block 3 ----
  rmsnorm128c_bf16_kernel<<<768, b256, 0, stream>>>(out_edge, lr_norm_e, enc);
  gemm_bf16_kernel<<<dim3(96,4), b256, 0, stream>>>(enc, wij3, preE, 512, 128);
  node_gemm_kernel<<<dim3(128,4), b128, 0, stream>>>(out_node, lr_win, 512, 64, NP3, 512, 0);
  env_kernel<<<4096, b256, 0, stream>>>(rbf, lr_env, env);
  angle_mfma_kernel<false><<<3072, b256, 0, stream>>>(hat, enc, wang3, wik3, preE, NP3, wo3T,
      angle_in, env, a_sw, lr_aproj, lr_eproj, out_edge, out_angle);

  // ---- block 4 ----
  rmsnorm128_bf16_kernel<<<2048, b256, 0, stream>>>(out_edge, ar_norm_e, enf, 8192);
  rmsnorm128_kernel<<<32, b256, 0, stream>>>(out_node, ar_norm_n, n_n, 128);
  gemm_bf16_kernel<<<dim3(256,4), b256, 0, stream>>>(enf, whe4, He, 512, 128);
  node_gemm_kernel<<<dim3(128,4), b128, 0, stream>>>(n_n, ar_win, 512, 128, npr, 1024, 0);
  node_gemm_kernel<<<dim3(128,4), b128, 0, stream>>>(n_n, ar_win, 512, 256, npr, 1024, 512);
  env_kernel<<<4096, b256, 0, stream>>>(rbf, ar_env, env);
  edge_fused_kernel<2><<<512, b256, 0, stream>>>(He, 512, 0, npr, next2e, wo_ar,
      nullptr, env, sw, ar_eproj, out_edge, partial);
  node_final4_kernel<<<128, b128, 0, stream>>>(partial, ar_nproj, out_node);

  (void)in_sizes; (void)n_in; (void)out_size; (void)ws_size;
}

// Round 5
// 402.083 us; speedup vs baseline: 4.8998x; 1.5067x over previous
//
#include <hip/hip_runtime.h>

#define A_SCALE_C 0.6454972243679028f   // (24/10)^-0.5
#define E_SCALE_C 0.3952847075210474f   // (64/10)^-0.5

typedef unsigned short u16;
typedef unsigned int u32;
typedef __attribute__((ext_vector_type(8))) short bf16x8;
typedef __attribute__((ext_vector_type(4))) float f32x4;

static __device__ __forceinline__ float waveSum(float v){
#pragma unroll
  for (int off = 32; off; off >>= 1) v += __shfl_xor(v, off, 64);
  return v;
}
static __device__ __forceinline__ float silu(float g){
  return g / (1.0f + __expf(-g));
}
static __device__ __forceinline__ float bf2f(u16 h){
  union { u32 u; float f; } x; x.u = ((u32)h) << 16; return x.f;
}
static __device__ __forceinline__ u16 f2bf(float f){
  union { float f; u32 u; } x; x.f = f;
  u32 r = x.u + 0x7FFFu + ((x.u >> 16) & 1u);
  return (u16)(r >> 16);
}

// ---------------- batched weight-transpose builder ----------------
// dst[(c0+c)<<dlog  + k0 + k] = bf16(src[(row0+k)*src_ld + c] * scale[k])
struct WtJob { const float* src; const float* scale; u16* dst;
               int src_ld, row0, c0, k0, dlog, kslog, C; };
struct WtJobs { WtJob j[18]; };

__global__ __launch_bounds__(256) void build_all_wt(WtJobs P){
  const WtJob J = P.j[blockIdx.y];
  const int ks = 1 << J.kslog;
  const int total = J.C << J.kslog;
  for (int idx = blockIdx.x*256 + threadIdx.x; idx < total; idx += gridDim.x*256){
    int c = idx >> J.kslog, k = idx & (ks-1);
    float s = J.scale ? J.scale[k] : 1.0f;
    J.dst[((size_t)(J.c0 + c) << J.dlog) + J.k0 + k] =
        f2bf(J.src[(size_t)(J.row0 + k)*J.src_ld + c] * s);
  }
}

// ---------------- small prep kernels ----------------

__global__ void scale_wout_kernel(const float* __restrict__ w, const float* __restrict__ nw,
                                  float* __restrict__ out){
  int idx = blockIdx.x*256 + threadIdx.x;
  out[idx] = w[idx] * nw[idx >> 7];
}

__global__ void copy4_kernel(const float4* __restrict__ src, float4* __restrict__ dst, int n4){
  int idx = blockIdx.x*256 + threadIdx.x;
  if (idx < n4) dst[idx] = src[idx];
}

__global__ void rmsnorm64_hat_kernel(const float* __restrict__ ang, u16* __restrict__ hat){
  int row = blockIdx.x*4 + (threadIdx.x >> 6);
  int lane = threadIdx.x & 63;
  float x = ang[(size_t)row*64 + lane];
  float ss = waveSum(x*x);
  float rs = rsqrtf(ss*(1.0f/64.0f) + 1e-6f);
  hat[(size_t)row*64 + lane] = f2bf(x*rs);
}

__global__ void rmsnorm128_bf16_kernel(const float* __restrict__ x, const float* __restrict__ w,
                                       u16* __restrict__ out, int nrows){
  int row = blockIdx.x*4 + (threadIdx.x >> 6);
  int lane = threadIdx.x & 63;
  if (row >= nrows) return;
  float2 v = *(const float2*)(x + (size_t)row*128 + lane*2);
  float ss = waveSum(v.x*v.x + v.y*v.y);
  float rs = rsqrtf(ss*(1.0f/128.0f) + 1e-6f);
  float2 wv = *(const float2*)(w + lane*2);
  u32 pk = (u32)f2bf(v.x*rs*wv.x) | ((u32)f2bf(v.y*rs*wv.y) << 16);
  *(u32*)(out + (size_t)row*128 + lane*2) = pk;
}

// compact rmsnorm + node append: enc_aug[3072][256] = [e_n bf16 | node bf16]
__global__ void rmsnorm128c_aug_kernel(const float* __restrict__ x, const float* __restrict__ w,
                                       const float* __restrict__ node, u16* __restrict__ out){
  int row = blockIdx.x*4 + (threadIdx.x >> 6);   // 0..3071
  int lane = threadIdx.x & 63;
  int loc = row/24;
  int src = loc*64 + (row - loc*24);
  float2 v = *(const float2*)(x + (size_t)src*128 + lane*2);
  float ss = waveSum(v.x*v.x + v.y*v.y);
  float rs = rsqrtf(ss*(1.0f/128.0f) + 1e-6f);
  float2 wv = *(const float2*)(w + lane*2);
  u32 pk = (u32)f2bf(v.x*rs*wv.x) | ((u32)f2bf(v.y*rs*wv.y) << 16);
  *(u32*)(out + (size_t)row*256 + lane*2) = pk;
  float2 nv = *(const float2*)(node + loc*128 + lane*2);
  u32 pn = (u32)f2bf(nv.x) | ((u32)f2bf(nv.y) << 16);
  *(u32*)(out + (size_t)row*256 + 128 + lane*2) = pn;
}

__global__ void rmsnorm128_kernel(const float* __restrict__ x, const float* __restrict__ w,
                                  float* __restrict__ out, int nrows){
  int row = blockIdx.x*4 + (threadIdx.x >> 6);
  int lane = threadIdx.x & 63;
  if (row >= nrows) return;
  float2 v = *(const float2*)(x + (size_t)row*128 + lane*2);
  float ss = waveSum(v.x*v.x + v.y*v.y);
  float rs = rsqrtf(ss*(1.0f/128.0f) + 1e-6f);
  float2 wv = *(const float2*)(w + lane*2);
  float2 o; o.x = v.x*rs*wv.x; o.y = v.y*rs*wv.y;
  *(float2*)(out + (size_t)row*128 + lane*2) = o;
}

__global__ __launch_bounds__(256) void env_kernel(const float* __restrict__ rbf,
                                                  const float* __restrict__ w,
                                                  float* __restrict__ env){
  __shared__ float wL[12*128];
  int t = threadIdx.x;
  for (int idx=t; idx<12*128; idx+=256) wL[idx] = w[idx];
  __syncthreads();
  int base = blockIdx.x*256 + t;
  int e = base >> 7, d = base & 127;
  float acc = 0.f;
#pragma unroll
  for (int k=0;k<12;k++) acc = fmaf(rbf[e*12+k], wL[k*128+d], acc);
  env[base] = acc;
}

__global__ __launch_bounds__(128) void node_gemm_kernel(const float* __restrict__ A,
    const float* __restrict__ B, int b_ld, int b_row0,
    float* __restrict__ C, int c_ld, int c_off){
  __shared__ float ar[128];
  int row = blockIdx.x, t = threadIdx.x;
  ar[t] = A[row*128 + t];
  __syncthreads();
  int col = blockIdx.y*128 + t;
  float acc = 0.f;
  for (int k=0;k<128;k++) acc = fmaf(ar[k], B[(size_t)(b_row0+k)*b_ld + col], acc);
  C[(size_t)row*c_ld + c_off + col] = acc;
}

// ---------------- MFMA GEMM: C[M][N]bf16 = A[M][K (lda)]bf16 @ Bt[N][K]^T ----------------
__global__ __launch_bounds__(256) void gemm_bf16_kernel(
    const u16* __restrict__ A, int lda, const u16* __restrict__ Bt, u16* __restrict__ C,
    int N, int K){
  __shared__ float cl[32*128];
  const int lane = threadIdx.x & 63, wave = threadIdx.x >> 6;
  const size_t arow = (size_t)blockIdx.x*32;
  const size_t bcol = (size_t)blockIdx.y*128 + wave*32;
  f32x4 acc00={0,0,0,0}, acc01={0,0,0,0}, acc10={0,0,0,0}, acc11={0,0,0,0};
  for (int k=0; k<K; k+=32){
    int ko = k + (lane>>4)*8;
    bf16x8 a0 = *(const bf16x8*)(A + (arow + (lane&15))*lda + ko);
    bf16x8 a1 = *(const bf16x8*)(A + (arow + 16 + (lane&15))*lda + ko);
    bf16x8 b0 = *(const bf16x8*)(Bt + (bcol + (lane&15))*K + ko);
    bf16x8 b1 = *(const bf16x8*)(Bt + (bcol + 16 + (lane&15))*K + ko);
    acc00 = __builtin_amdgcn_mfma_f32_16x16x32_bf16(a0, b0, acc00, 0,0,0);
    acc01 = __builtin_amdgcn_mfma_f32_16x16x32_bf16(a0, b1, acc01, 0,0,0);
    acc10 = __builtin_amdgcn_mfma_f32_16x16x32_bf16(a1, b0, acc10, 0,0,0);
    acc11 = __builtin_amdgcn_mfma_f32_16x16x32_bf16(a1, b1, acc11, 0,0,0);
  }
  const int cr = (lane>>4)*4, cc = wave*32 + (lane&15);
#pragma unroll
  for (int q=0;q<4;q++){
    cl[(cr+q)*128 + cc]      = acc00[q];
    cl[(cr+q)*128 + cc+16]   = acc01[q];
    cl[(16+cr+q)*128 + cc]    = acc10[q];
    cl[(16+cr+q)*128 + cc+16] = acc11[q];
  }
  __syncthreads();
  const int t = threadIdx.x;
  size_t base = arow*N + (size_t)blockIdx.y*128;
#pragma unroll
  for (int i=0;i<16;i++){
    int idx = i*256 + t; int r = idx>>7, c = idx&127;
    C[base + (size_t)r*N + c] = f2bf(cl[idx]);
  }
}

// ---------------- fused angle kernel v2: 2 segments (48 rows) per block ----------------
// hidden[r][c] = (hat @ wang)[r][c] + preE[seg(r)][c] + preK[loc*24 + r%24][c]
// grid 1536, 512 threads (8 waves).
template<bool IS_BLK1>
__global__ __launch_bounds__(512, 4) void angle2_kernel(
    const u16* __restrict__ hat,      // [73728][64]
    const u16* __restrict__ preE,     // [3072][HW]
    const u16* __restrict__ preK,     // [3072][HW] (node folded)
    const u16* __restrict__ wangT,    // [HW][64]
    const u16* __restrict__ woT,      // [128][256]
    const float* __restrict__ angle,
    const float* __restrict__ env, const float* __restrict__ a_sw,
    const float* __restrict__ aproj, const float* __restrict__ eproj,
    float* __restrict__ edge_out, float* __restrict__ angle_out)
{
  constexpr int HW = IS_BLK1 ? 640 : 512;
  constexpr int NT = IS_BLK1 ? 5 : 4;
  constexpr int PRE_B  = 26*HW*2;                  // preL bytes
  constexpr int VGN_O  = PRE_B;
  constexpr int GATE_O = VGN_O + 48*264*2;
  constexpr int SS_O   = GATE_O + (IS_BLK1 ? 48*132*2 : 0);
  constexpr int RS_O   = SS_O + 8*48*4;
  constexpr int SEG_O  = RS_O + 192;
  constexpr int LDS_B  = SEG_O + (IS_BLK1 ? 0 : 1024);
  __shared__ __align__(16) char ldsRaw[LDS_B];
  u16*   preL   = (u16*)ldsRaw;
  u16*   vgn    = (u16*)(ldsRaw + VGN_O);
  u16*   gateLb = (u16*)(ldsRaw + GATE_O);
  float* ssL    = (float*)(ldsRaw + SS_O);
  float* rsL    = (float*)(ldsRaw + RS_O);
  float* segL   = (float*)(ldsRaw + SEG_O);
  float* msgL   = (float*)ldsRaw;                  // [48][132] alias over preL

  const int t = threadIdx.x, lane = t & 63, w = t >> 6;
  const int l15 = lane & 15, l4 = lane >> 4;
  const int blk = blockIdx.x;
  const int loc = blk/12, pr = blk - loc*12, j0 = pr*2;
  const int s0 = loc*24 + j0;
  const int loc24 = loc*24;
  const int hbase = s0*24;

  // ---- stage preL: rows 0..23 = preK[loc], rows 24,25 = preE[s0],preE[s1] ----
  for (int idx = t; idx < 13*HW; idx += 512){     // u32 units
    int row = idx/(HW/2), c2 = idx - row*(HW/2);
    const u16* src = (row < 24) ? (preK + (size_t)(loc24+row)*HW)
                                : (preE + (size_t)(s0 + row-24)*HW);
    ((u32*)preL)[row*(HW/2) + c2] = ((const u32*)src)[c2];
  }

  // ---- hidden MFMA: K=64 (hat only) ----
  f32x4 acc[3][NT];
#pragma unroll
  for (int m=0;m<3;m++)
#pragma unroll
    for (int nt=0;nt<NT;nt++) acc[m][nt] = (f32x4){0.f,0.f,0.f,0.f};

#pragma unroll
  for (int kk=0; kk<2; kk++){
    bf16x8 a[3];
#pragma unroll
    for (int m=0;m<3;m++)
      a[m] = *(const bf16x8*)(hat + (size_t)(hbase + m*16 + l15)*64 + kk*32 + l4*8);
#pragma unroll
    for (int nt=0; nt<NT; nt++){
      int col0 = (nt<2) ? (32*w + nt*16) : ((nt<4) ? (256 + 32*w + (nt-2)*16) : (512 + 16*w));
      bf16x8 b = *(const bf16x8*)(wangT + (size_t)(col0 + l15)*64 + kk*32 + l4*8);
#pragma unroll
      for (int m=0;m<3;m++)
        acc[m][nt] = __builtin_amdgcn_mfma_f32_16x16x32_bf16(a[m], b, acc[m][nt], 0,0,0);
    }
  }
  __syncthreads();   // preL staged

  // ---- epilogue A: add preE/preK, silu, vgn bf16 + ss + gate ----
  float ss[3][4] = {{0,0,0,0},{0,0,0,0},{0,0,0,0}};
#pragma unroll
  for (int m=0;m<3;m++){
#pragma unroll
    for (int q=0;q<4;q++){
      int r = m*16 + l4*4 + q;
      int rr = (r >= 24) ? r-24 : r;
      int sl = (r >= 24) ? 25 : 24;
#pragma unroll
      for (int vt=0; vt<2; vt++){
        int cv = 32*w + vt*16 + l15;
        float pv = bf2f(preL[rr*HW + cv])     + bf2f(preL[sl*HW + cv]);
        float pg = bf2f(preL[rr*HW + 256+cv]) + bf2f(preL[sl*HW + 256+cv]);
        float v = acc[m][vt][q] + pv;
        float g = acc[m][2+vt][q] + pg;
        float x = v * silu(g);
        ss[m][q] += x*x;
        vgn[r*264 + cv] = f2bf(x);
      }
      if constexpr (IS_BLK1){
        int cg = 16*w + l15;
        float gt = acc[m][4][q] + bf2f(preL[rr*HW + 512+cg]) + bf2f(preL[sl*HW + 512+cg]);
        gateLb[r*132 + cg] = f2bf(gt * A_SCALE_C);
      }
    }
  }
#pragma unroll
  for (int m=0;m<3;m++)
#pragma unroll
    for (int q=0;q<4;q++){
      float s = ss[m][q];
      s += __shfl_xor(s,1,64); s += __shfl_xor(s,2,64);
      s += __shfl_xor(s,4,64); s += __shfl_xor(s,8,64);
      if (l15 == 0) ssL[w*48 + m*16 + l4*4 + q] = s;
    }
  __syncthreads();
  if (t < 48){
    float s_ = 0.f;
#pragma unroll
    for (int k=0;k<8;k++) s_ += ssL[k*48 + t];
    rsL[t] = rsqrtf(s_*(1.0f/256.0f) + 1e-6f);
  }
  __syncthreads();

  // ---- out-GEMM MFMA: msg = vg @ woT, K=256; 1 col-tile per wave ----
  f32x4 mac[3];
#pragma unroll
  for (int m=0;m<3;m++) mac[m] = (f32x4){0,0,0,0};
  const int oc = 16*w + l15;
#pragma unroll
  for (int kk=0; kk<8; kk++){
    bf16x8 b = *(const bf16x8*)(woT + (size_t)oc*256 + kk*32 + l4*8);
#pragma unroll
    for (int m=0;m<3;m++){
      bf16x8 a = *(const bf16x8*)&vgn[(m*16 + l15)*264 + kk*32 + l4*8];
      mac[m] = __builtin_amdgcn_mfma_f32_16x16x32_bf16(a, b, mac[m], 0,0,0);
    }
  }
  float rsv[3][4];
#pragma unroll
  for (int m=0;m<3;m++)
#pragma unroll
    for (int q=0;q<4;q++) rsv[m][q] = rsL[m*16 + l4*4 + q];
#pragma unroll
  for (int m=0;m<3;m++)
#pragma unroll
    for (int q=0;q<4;q++)
      msgL[(m*16 + l4*4 + q)*132 + 16*w + l15] = mac[m][q] * rsv[m][q];
  __syncthreads();

  // ---- epilogue B ----
  if constexpr (IS_BLK1){
    if (t < 256){
      int s = t>>7, c = t&127;
      float ex[24]; float mx = -1e30f;
#pragma unroll
      for (int k=0;k<24;k++){ ex[k] = bf2f(gateLb[(s*24+k)*132 + c]); mx = fmaxf(mx, ex[k]); }
      float S = 0.f;
#pragma unroll
      for (int k=0;k<24;k++){ ex[k] = __expf(ex[k] - mx); S += ex[k]; }
      float inv = 1.f/(S + 1e-12f);
      float delta = 0.f;
#pragma unroll
      for (int k=0;k<24;k++) delta += msgL[(s*24+k)*132 + c] * ex[k];
      edge_out[(size_t)(loc*64 + j0 + s)*128 + c] += delta * inv;
    }
  } else {
    { // angle update: 8 groups x 6 rows
      const int c = t & 63, ra = (t >> 6) * 6;
      float aacc[6] = {0,0,0,0,0,0};
      for (int dd=0; dd<128; dd++){
        float wv = aproj[dd*64 + c];
#pragma unroll
        for (int i=0;i<6;i++) aacc[i] = fmaf(msgL[(ra+i)*132 + dd], wv, aacc[i]);
      }
      const size_t abase = (size_t)hbase;
#pragma unroll
      for (int i=0;i<6;i++){
        size_t a = abase + ra + i;
        angle_out[a*64 + c] = angle[a*64 + c] + aacc[i] * a_sw[a];
      }
    }
    if (t < 256){
      int s = t>>7, c = t&127;
      float sg_ = 0.f;
#pragma unroll
      for (int k=0;k<24;k++)
        sg_ += msgL[(s*24+k)*132 + c] * env[(size_t)(loc*64 + k)*128 + c]
             * a_sw[(size_t)(s0+s)*24 + k];
      segL[s*128 + c] = sg_;
    }
    __syncthreads();
    if (t < 256){
      int s = t>>7, c = t&127;
      float acc2 = 0.f;
      for (int dd=0; dd<128; dd++) acc2 = fmaf(segL[s*128 + dd], eproj[dd*128 + c], acc2);
      edge_out[(size_t)(loc*64 + j0 + s)*128 + c] += acc2 * A_SCALE_C;
    }
  }
}

// blk2 per-dim softmax over each node's 64 edges; gate from He cols 1024..1151
__global__ __launch_bounds__(256) void scores_kernel(const u16* __restrict__ He,
                                                     float* __restrict__ scores){
  __shared__ float s[64*128];
  const int t = threadIdx.x, n = blockIdx.x;
  for (int idx=t; idx<64*128; idx+=256){
    int r = idx>>7, c = idx&127;
    s[idx] = bf2f(He[(size_t)(n*64+r)*1152 + 1024 + c]) * E_SCALE_C;
  }
  __syncthreads();
  if (t < 128){
    float m = -1e30f;
    for (int r=0;r<64;r++) m = fmaxf(m, s[r*128 + t]);
    float S = 0.f;
    for (int r=0;r<64;r++) S += __expf(s[r*128 + t] - m);
    float inv = 1.f/(S + 1e-12f);
    for (int r=0;r<64;r++)
      scores[(size_t)(n*64 + r)*128 + t] = __expf(s[r*128 + t] - m) * inv;
  }
}

// ---------------- fused edge kernel (blocks 2 and 4) ----------------
template<int MODE>
__global__ __launch_bounds__(256) void edge_fused_kernel(
    const u16* __restrict__ He, int he_ld, int he_off,
    const float* __restrict__ NPt,      // [128][1024] self(512)|nbr(512)
    const int* __restrict__ next2e,
    const float* __restrict__ wout,
    const float* __restrict__ scores, const float* __restrict__ env,
    const float* __restrict__ sw, const float* __restrict__ eproj,
    float* __restrict__ edge_out, float* __restrict__ partial){
  __shared__ float vg[16*256];
  __shared__ float msgL[16*128];
  __shared__ float rsL[16];
  __shared__ int nxL[16];
  const int t = threadIdx.x, g = blockIdx.x, e0 = g*16, n = e0 >> 6;
  if (t < 16) nxL[t] = next2e[e0 + t];
  __syncthreads();
  float bv = NPt[n*1024 + t], bg = NPt[n*1024 + 256 + t];
  for (int r=0;r<16;r++){
    int nx = nxL[r];
    float v  = bf2f(He[(size_t)(e0+r)*he_ld + he_off + t])       + bv + NPt[nx*1024 + 512 + t];
    float gg = bf2f(He[(size_t)(e0+r)*he_ld + he_off + 256 + t]) + bg + NPt[nx*1024 + 768 + t];
    vg[r*256 + t] = v * silu(gg);
  }
  __syncthreads();
  {
    const int wv = t >> 6, lane = t & 63;
    for (int r=wv; r<16; r+=4){
      const float4 v = *(const float4*)&vg[r*256 + lane*4];
      float ss = waveSum(v.x*v.x + v.y*v.y + v.z*v.z + v.w*v.w);
      if (lane == 0) rsL[r] = rsqrtf(ss*(1.0f/256.0f) + 1e-6f);
    }
  }
  __syncthreads();
  const int d  = t & 127;
  const int rg = (t >> 7) * 8;
  float macc[8];
#pragma unroll
  for (int i=0;i<8;i++) macc[i]=0.f;
  for (int c=0;c<256;c+=4){
    float w0 = wout[(c+0)*128 + d];
    float w1 = wout[(c+1)*128 + d];
    float w2 = wout[(c+2)*128 + d];
    float w3 = wout[(c+3)*128 + d];
#pragma unroll
    for (int i=0;i<8;i++){
      const float4 v = *(const float4*)&vg[(rg+i)*256 + c];
      macc[i] = fmaf(v.x,w0,macc[i]); macc[i] = fmaf(v.y,w1,macc[i]);
      macc[i] = fmaf(v.z,w2,macc[i]); macc[i] = fmaf(v.w,w3,macc[i]);
    }
  }
#pragma unroll
  for (int i=0;i<8;i++) msgL[(rg+i)*128 + d] = macc[i] * rsL[rg+i];
  __syncthreads();

  if constexpr (MODE == 0){
    if (t < 128){
      float p = 0.f;
#pragma unroll
      for (int r=0;r<16;r++) p += msgL[r*128 + t] * scores[(size_t)(e0+r)*128 + t];
      partial[g*128 + t] = p;
    }
  } else if constexpr (MODE == 1){
#pragma unroll
    for (int i=0;i<8;i++)
      edge_out[(size_t)(e0+rg+i)*128 + d] += msgL[(rg+i)*128 + d];
  } else {
    float eacc[8];
#pragma unroll
    for (int i=0;i<8;i++) eacc[i]=0.f;
    for (int dd=0; dd<128; dd++){
      float wv = eproj[dd*128 + d];
#pragma unroll
      for (int i=0;i<8;i++) eacc[i] = fmaf(msgL[(rg+i)*128 + dd], wv, eacc[i]);
    }
#pragma unroll
    for (int i=0;i<8;i++)
      edge_out[(size_t)(e0+rg+i)*128 + d] += eacc[i];
    if (t < 128){
      float p = 0.f;
#pragma unroll
      for (int r=0;r<16;r++)
        p += msgL[r*128 + t] * env[(size_t)(e0+r)*128 + t] * sw[e0 + r];
      partial[g*128 + t] = p;
    }
  }
}

__global__ void node_add4_kernel(const float* __restrict__ partial, float* __restrict__ node_out){
  int n = blockIdx.x, t = threadIdx.x;
  node_out[n*128 + t] += partial[(4*n)*128+t] + partial[(4*n+1)*128+t]
                       + partial[(4*n+2)*128+t] + partial[(4*n+3)*128+t];
}

__global__ void node_final4_kernel(const float* __restrict__ partial,
                                   const float* __restrict__ nproj,
                                   float* __restrict__ node_out){
  __shared__ float seg[128];
  int n = blockIdx.x, t = threadIdx.x;
  seg[t] = partial[(4*n)*128+t] + partial[(4*n+1)*128+t]
         + partial[(4*n+2)*128+t] + partial[(4*n+3)*128+t];
  __syncthreads();
  float acc = 0.f;
  for (int dd=0; dd<128; dd++) acc = fmaf(seg[dd], nproj[dd*128 + t], acc);
  node_out[n*128 + t] += acc * E_SCALE_C;
}

// ---------------- launch ----------------
extern "C" void kernel_launch(void* const* d_in, const int* in_sizes, int n_in,
                              void* d_out, int out_size, void* d_ws, size_t ws_size,
                              hipStream_t stream){
  const float* node_in  = (const float*)d_in[0];
  const float* edge_in  = (const float*)d_in[1];
  const float* angle_in = (const float*)d_in[2];
  const float* sw       = (const float*)d_in[3];
  const float* a_sw     = (const float*)d_in[4];
  const float* rbf      = (const float*)d_in[5];
  const int*   edge_index = (const int*)d_in[6];
  const float* la_norm_e = (const float*)d_in[8];
  const float* la_norm_a = (const float*)d_in[9];
  const float* la_win    = (const float*)d_in[10];
  const float* la_nw     = (const float*)d_in[11];
  const float* la_wout   = (const float*)d_in[12];
  const float* la_gate   = (const float*)d_in[13];
  const float* aa_norm_n = (const float*)d_in[14];
  const float* aa_norm_e = (const float*)d_in[15];
  const float* aa_win    = (const float*)d_in[16];
  const float* aa_nw     = (const float*)d_in[17];
  const float* aa_wout   = (const float*)d_in[18];
  const float* aa_src_gate = (const float*)d_in[19];
  const float* ae_win    = (const float*)d_in[20];
  const float* ae_nw     = (const float*)d_in[21];
  const float* ae_wout   = (const float*)d_in[22];
  const float* lr_norm_e = (const float*)d_in[23];
  const float* lr_norm_a = (const float*)d_in[24];
  const float* lr_win    = (const float*)d_in[25];
  const float* lr_nw     = (const float*)d_in[26];
  const float* lr_wout   = (const float*)d_in[27];
  const float* lr_env    = (const float*)d_in[28];
  const float* lr_eproj  = (const float*)d_in[29];
  const float* lr_aproj  = (const float*)d_in[30];
  const float* ar_norm_n = (const float*)d_in[31];
  const float* ar_norm_e = (const float*)d_in[32];
  const float* ar_win    = (const float*)d_in[33];
  const float* ar_nw     = (const float*)d_in[34];
  const float* ar_wout   = (const float*)d_in[35];
  const float* ar_env    = (const float*)d_in[36];
  const float* ar_nproj  = (const float*)d_in[37];
  const float* ar_eproj  = (const float*)d_in[38];

  float* out_node  = (float*)d_out;
  float* out_edge  = out_node + 128*128;
  float* out_angle = out_edge + (size_t)8192*128;

  float* p = (float*)d_ws;
  float* hat_f   = p; p += 2359296;   // bf16 [73728][64]  (FIXED: was 1179648 -> overlapped enca/preE)
  float* enca_f  = p; p += 393216;    // bf16 [3072][256]
  float* preE_f  = p; p += 983040;    // bf16 [3072][640]
  float* preK_f  = p; p += 983040;    // bf16 [3072][640]
  float* He_f    = p; p += 4718592;   // bf16 [8192][1152]
  float* enf_f   = p; p += 524288;    // bf16 [8192][128]
  float* wang1_f = p; p += 20480;     // bf16 [640][64]
  float* wang3_f = p; p += 16384;     // bf16 [512][64]
  float* wij1_f  = p; p += 40960;     // bf16 [640][128]
  float* wij3_f  = p; p += 32768;     // bf16 [512][128]
  float* wik1_f  = p; p += 81920;     // bf16 [640][256]
  float* wik3_f  = p; p += 65536;     // bf16 [512][256]
  float* wo1T_f  = p; p += 16384;     // bf16 [128][256]
  float* wo3T_f  = p; p += 16384;     // bf16 [128][256]
  float* whe2_f  = p; p += 73728;     // bf16 [1152][128]
  float* whe4_f  = p; p += 32768;     // bf16 [512][128]
  float* npa     = p; p += 131072;    // fp32 [128][1024]
  float* npe     = p; p += 131072;
  float* npr     = p; p += 131072;
  float* n_n     = p; p += 16384;
  float* wo_aa   = p; p += 32768;
  float* wo_ae   = p; p += 32768;
  float* wo_ar   = p; p += 32768;
  float* scores2 = p; p += 1048576;
  float* env     = p; p += 1048576;
  float* partial = p; p += 65536;

  u16* hat  = (u16*)hat_f;
  u16* enca = (u16*)enca_f;
  u16* preE = (u16*)preE_f;
  u16* preK = (u16*)preK_f;
  u16* He   = (u16*)He_f;
  u16* enf  = (u16*)enf_f;
  u16* wang1= (u16*)wang1_f;
  u16* wang3= (u16*)wang3_f;
  u16* wij1 = (u16*)wij1_f;
  u16* wij3 = (u16*)wij3_f;
  u16* wik1 = (u16*)wik1_f;
  u16* wik3 = (u16*)wik3_f;
  u16* wo1T = (u16*)wo1T_f;
  u16* wo3T = (u16*)wo3T_f;
  u16* whe2 = (u16*)whe2_f;
  u16* whe4 = (u16*)whe4_f;

  dim3 b512(512), b256(256), b128(128);
  const int* next2e = edge_index + 8192;

  // ---- prep: all transposed bf16 weights in one batched launch ----
  WtJobs jobs;
  int nj = 0;
  auto add = [&](const float* src, const float* scale, u16* dst,
                 int ld, int row0, int c0, int k0, int dlog, int kslog, int C){
    jobs.j[nj++] = WtJob{src, scale, dst, ld, row0, c0, k0, dlog, kslog, C};
  };
  add(la_win, la_norm_a, wang1, 512, 0,   0,   0,   6, 6, 512);
  add(la_gate,la_norm_a, wang1, 128, 0,   512, 0,   6, 6, 128);
  add(la_win, nullptr,   wij1,  512, 192, 0,   0,   7, 7, 512);
  add(la_gate,nullptr,   wij1,  128, 192, 512, 0,   7, 7, 128);
  add(la_win, nullptr,   wik1,  512, 320, 0,   0,   8, 7, 512);
  add(la_gate,nullptr,   wik1,  128, 320, 512, 0,   8, 7, 128);
  add(la_win, nullptr,   wik1,  512, 64,  0,   128, 8, 7, 512);
  add(la_gate,nullptr,   wik1,  128, 64,  512, 128, 8, 7, 128);
  add(la_wout,la_nw,     wo1T,  128, 0,   0,   0,   8, 8, 128);
  add(lr_win, lr_norm_a, wang3, 512, 0,   0,   0,   6, 6, 512);
  add(lr_win, nullptr,   wij3,  512, 192, 0,   0,   7, 7, 512);
  add(lr_win, nullptr,   wik3,  512, 320, 0,   0,   8, 7, 512);
  add(lr_win, nullptr,   wik3,  512, 64,  0,   128, 8, 7, 512);
  add(lr_wout,lr_nw,     wo3T,  128, 0,   0,   0,   8, 8, 128);
  add(aa_win, nullptr,   whe2,  512, 0,   0,   0,   7, 7, 512);
  add(ae_win, nullptr,   whe2,  512, 0,   512, 0,   7, 7, 512);
  add(aa_src_gate,nullptr,whe2, 128, 0,   1024,0,   7, 7, 128);
  add(ar_win, nullptr,   whe4,  512, 0,   0,   0,   7, 7, 512);
  build_all_wt<<<dim3(64, 18), b256, 0, stream>>>(jobs);

  scale_wout_kernel<<<128, b256, 0, stream>>>(aa_wout, aa_nw, wo_aa);
  scale_wout_kernel<<<128, b256, 0, stream>>>(ae_wout, ae_nw, wo_ae);
  scale_wout_kernel<<<128, b256, 0, stream>>>(ar_wout, ar_nw, wo_ar);
  rmsnorm64_hat_kernel<<<18432, b256, 0, stream>>>(angle_in, hat);
  copy4_kernel<<<1024, b256, 0, stream>>>((const float4*)edge_in, (float4*)out_edge, 262144);
  copy4_kernel<<<16,   b256, 0, stream>>>((const float4*)node_in, (float4*)out_node, 4096);

  // ---- block 1 ----
  rmsnorm128c_aug_kernel<<<768, b256, 0, stream>>>(edge_in, la_norm_e, node_in, enca);
  gemm_bf16_kernel<<<dim3(96,5), b256, 0, stream>>>(enca, 256, wij1, preE, 640, 128);
  gemm_bf16_kernel<<<dim3(96,5), b256, 0, stream>>>(enca, 256, wik1, preK, 640, 256);
  angle2_kernel<true><<<1536, b512, 0, stream>>>(hat, preE, preK, wang1, wo1T,
      angle_in, nullptr, nullptr, nullptr, nullptr, out_edge, nullptr);

  // ---- block 2 ----
  rmsnorm128_bf16_kernel<<<2048, b256, 0, stream>>>(out_edge, aa_norm_e, enf, 8192);
  rmsnorm128_kernel<<<32, b256, 0, stream>>>(node_in, aa_norm_n, n_n, 128);
  gemm_bf16_kernel<<<dim3(256,9), b256, 0, stream>>>(enf, 128, whe2, He, 1152, 128);
  node_gemm_kernel<<<dim3(128,4), b128, 0, stream>>>(n_n, aa_win, 512, 128, npa, 1024, 0);
  node_gemm_kernel<<<dim3(128,4), b128, 0, stream>>>(n_n, aa_win, 512, 256, npa, 1024, 512);
  node_gemm_kernel<<<dim3(128,4), b128, 0, stream>>>(n_n, ae_win, 512, 128, npe, 1024, 0);
  node_gemm_kernel<<<dim3(128,4), b128, 0, stream>>>(n_n, ae_win, 512, 256, npe, 1024, 512);
  scores_kernel<<<128, b256, 0, stream>>>(He, scores2);
  edge_fused_kernel<0><<<512, b256, 0, stream>>>(He, 1152, 0, npa, next2e, wo_aa,
      scores2, nullptr, nullptr, nullptr, nullptr, partial);
  edge_fused_kernel<1><<<512, b256, 0, stream>>>(He, 1152, 512, npe, next2e, wo_ae,
      nullptr, nullptr, nullptr, nullptr, out_edge, nullptr);
  node_add4_kernel<<<128, b128, 0, stream>>>(partial, out_node);

  // ---- block 3 ----
  rmsnorm128c_aug_kernel<<<768, b256, 0, stream>>>(out_edge, lr_norm_e, out_node, enca);
  gemm_bf16_kernel<<<dim3(96,4), b256, 0, stream>>>(enca, 256, wij3, preE, 512, 128);
  gemm_bf16_kernel<<<dim3(96,4), b256, 0, stream>>>(enca, 256, wik3, preK, 512, 256);
  env_kernel<<<4096, b256, 0, stream>>>(rbf, lr_env, env);
  angle2_kernel<false><<<1536, b512, 0, stream>>>(hat, preE, preK, wang3, wo3T,
      angle_in, env, a_sw, lr_aproj, lr_eproj, out_edge, out_angle);

  // ---- block 4 ----
  rmsnorm128_bf16_kernel<<<2048, b256, 0, stream>>>(out_edge, ar_norm_e, enf, 8192);
  rmsnorm128_kernel<<<32, b256, 0, stream>>>(out_node, ar_norm_n, n_n, 128);
  gemm_bf16_kernel<<<dim3(256,4), b256, 0, stream>>>(enf, 128, whe4, He, 512, 128);
  node_gemm_kernel<<<dim3(128,4), b128, 0, stream>>>(n_n, ar_win, 512, 128, npr, 1024, 0);
  node_gemm_kernel<<<dim3(128,4), b128, 0, stream>>>(n_n, ar_win, 512, 256, npr, 1024, 512);
  env_kernel<<<4096, b256, 0, stream>>>(rbf, ar_env, env);
  edge_fused_kernel<2><<<512, b256, 0, stream>>>(He, 512, 0, npr, next2e, wo_ar,
      nullptr, env, sw, ar_eproj, out_edge, partial);
  node_final4_kernel<<<128, b128, 0, stream>>>(partial, ar_nproj, out_node);

  (void)in_sizes; (void)n_in; (void)out_size; (void)ws_size;
}